// Round 1
// baseline (1998.706 us; speedup 1.0000x reference)
//
#include <hip/hip_runtime.h>
#include <math.h>

#define CD 768
#define DH 128
#define MH 6

// -------------------- wave / block reduction --------------------
static __device__ __forceinline__ float wred(float v) {
#pragma unroll
  for (int off = 32; off > 0; off >>= 1) v += __shfl_down(v, off, 64);
  return v;
}

// -------------------- LayerNorm: one block per row of 768 --------------------
__global__ __launch_bounds__(256) void ln_kernel(const float* __restrict__ in,
                                                 const float* __restrict__ g,
                                                 const float* __restrict__ b,
                                                 float* __restrict__ out) {
  int row = blockIdx.x;
  const float* xp = in + (size_t)row * CD;
  float* op = out + (size_t)row * CD;
  int t = threadIdx.x;
  float v0 = xp[t], v1 = xp[t + 256], v2 = xp[t + 512];
  __shared__ float wsum[4];
  __shared__ float stat[2];
  int wid = t >> 6, lane = t & 63;
  float s = wred(v0 + v1 + v2);
  if (lane == 0) wsum[wid] = s;
  __syncthreads();
  if (t == 0) stat[0] = (wsum[0] + wsum[1] + wsum[2] + wsum[3]) * (1.0f / 768.0f);
  __syncthreads();
  float mu = stat[0];
  float d0 = v0 - mu, d1 = v1 - mu, d2 = v2 - mu;
  float q = wred(d0 * d0 + d1 * d1 + d2 * d2);
  if (lane == 0) wsum[wid] = q;
  __syncthreads();
  if (t == 0) {
    float var = (wsum[0] + wsum[1] + wsum[2] + wsum[3]) * (1.0f / 768.0f);
    stat[1] = 1.0f / sqrtf(var + 1e-6f);
  }
  __syncthreads();
  float rstd = stat[1];
  op[t]       = d0 * rstd * g[t]       + b[t];
  op[t + 256] = d1 * rstd * g[t + 256] + b[t + 256];
  op[t + 512] = d2 * rstd * g[t + 512] + b[t + 512];
}

// -------------------- fp32 tiled GEMM: out = epilogue(A @ W + bias) --------------------
// A: (M,K) row-major, W: (K,N) row-major, out: (M,N).
// MODE 0: out = acc + bias
// MODE 1: out = res + gamma * (acc + bias)   (gamma per-column)
// MODE 2: out = res + (acc + bias)
// Requires: M % 128 == 0, K % 16 == 0, N % 4 == 0 (bounds-checked on N).
template <int MODE>
__global__ __launch_bounds__(256) void gemm128(const float* __restrict__ A,
                                               const float* __restrict__ W,
                                               const float* __restrict__ bias,
                                               const float* __restrict__ res,
                                               const float* __restrict__ gamma,
                                               float* __restrict__ out,
                                               int M, int N, int K) {
  __shared__ float As[16][132];  // k-major, padded (132*4=528B, 16B-aligned rows)
  __shared__ float Bs[16][132];
  int tid = threadIdx.x;
  int bm = blockIdx.y * 128;
  int bn = blockIdx.x * 128;
  int tx = tid & 15, ty = tid >> 4;
  int arow = tid >> 2;         // 0..63
  int ak = (tid & 3) << 2;     // 0,4,8,12
  int brow = tid >> 4;         // 0..15
  int bcol = (tid & 15) << 3;  // 0..120

  float acc[8][8];
#pragma unroll
  for (int i = 0; i < 8; ++i)
#pragma unroll
    for (int j = 0; j < 8; ++j) acc[i][j] = 0.0f;

  const float* Ap = A + (size_t)(bm + arow) * K + ak;
  const float* Ap2 = Ap + (size_t)64 * K;

  for (int k0 = 0; k0 < K; k0 += 16) {
    float4 a0 = *(const float4*)(Ap + k0);
    float4 a1 = *(const float4*)(Ap2 + k0);
    float4 b0 = {0.f, 0.f, 0.f, 0.f}, b1 = {0.f, 0.f, 0.f, 0.f};
    int gn0 = bn + bcol, gn1 = gn0 + 4;
    const float* Wp = W + (size_t)(k0 + brow) * N;
    if (gn0 < N) b0 = *(const float4*)(Wp + gn0);
    if (gn1 < N) b1 = *(const float4*)(Wp + gn1);
    __syncthreads();
    As[ak + 0][arow] = a0.x;
    As[ak + 1][arow] = a0.y;
    As[ak + 2][arow] = a0.z;
    As[ak + 3][arow] = a0.w;
    As[ak + 0][arow + 64] = a1.x;
    As[ak + 1][arow + 64] = a1.y;
    As[ak + 2][arow + 64] = a1.z;
    As[ak + 3][arow + 64] = a1.w;
    *(float4*)&Bs[brow][bcol] = b0;
    *(float4*)&Bs[brow][bcol + 4] = b1;
    __syncthreads();
#pragma unroll
    for (int k = 0; k < 16; ++k) {
      float4 af0 = *(const float4*)&As[k][ty * 4];
      float4 af1 = *(const float4*)&As[k][ty * 4 + 64];
      float4 bf0 = *(const float4*)&Bs[k][tx * 4];
      float4 bf1 = *(const float4*)&Bs[k][tx * 4 + 64];
      float ar[8] = {af0.x, af0.y, af0.z, af0.w, af1.x, af1.y, af1.z, af1.w};
      float br[8] = {bf0.x, bf0.y, bf0.z, bf0.w, bf1.x, bf1.y, bf1.z, bf1.w};
#pragma unroll
      for (int i = 0; i < 8; ++i)
#pragma unroll
        for (int j = 0; j < 8; ++j) acc[i][j] = fmaf(ar[i], br[j], acc[i][j]);
    }
  }

#pragma unroll
  for (int i = 0; i < 8; ++i) {
    int row = bm + ((i < 4) ? (ty * 4 + i) : (64 + ty * 4 + (i - 4)));
#pragma unroll
    for (int jh = 0; jh < 2; ++jh) {
      int col = bn + jh * 64 + tx * 4;
      if (col < N) {
        float4 bb = *(const float4*)(bias + col);
        float bv[4] = {bb.x, bb.y, bb.z, bb.w};
        float v[4];
#pragma unroll
        for (int j = 0; j < 4; ++j) v[j] = acc[i][jh * 4 + j] + bv[j];
        if (MODE == 1) {
          float4 gg = *(const float4*)(gamma + col);
          float4 rr = *(const float4*)(res + (size_t)row * N + col);
          float gv[4] = {gg.x, gg.y, gg.z, gg.w};
          float rv[4] = {rr.x, rr.y, rr.z, rr.w};
#pragma unroll
          for (int j = 0; j < 4; ++j) v[j] = rv[j] + gv[j] * v[j];
        } else if (MODE == 2) {
          float4 rr = *(const float4*)(res + (size_t)row * N + col);
          float rv[4] = {rr.x, rr.y, rr.z, rr.w};
#pragma unroll
          for (int j = 0; j < 4; ++j) v[j] = rv[j] + v[j];
        }
        float4 o;
        o.x = v[0]; o.y = v[1]; o.z = v[2]; o.w = v[3];
        *(float4*)(out + (size_t)row * N + col) = o;
      }
    }
  }
}

// -------------------- softmax over last LP entries, one thread per (b,q,m) --------------------
__global__ void softmax_lp(float* __restrict__ a, int total, int LP) {
  int i = blockIdx.x * blockDim.x + threadIdx.x;
  if (i >= total) return;
  float* p = a + (size_t)i * LP;
  float mx = -1e30f;
  for (int j = 0; j < LP; ++j) mx = fmaxf(mx, p[j]);
  float s = 0.0f;
  for (int j = 0; j < LP; ++j) {
    float e = expf(p[j] - mx);
    p[j] = e;
    s += e;
  }
  float inv = 1.0f / s;
  for (int j = 0; j < LP; ++j) p[j] *= inv;
}

// -------------------- Injector sampling: queries=ViT 32x32, kv=pyramid (3 levels) -----------
// v: (B,5376,768) token-major; offs: (B,1024,6,3,4,2); aw: (B,1024,6,12); out: (B,1024,768)
__global__ __launch_bounds__(128) void sample_inj(const float* __restrict__ v,
                                                  const float* __restrict__ offs,
                                                  const float* __restrict__ aw,
                                                  float* __restrict__ out) {
  int bqm = blockIdx.x;
  int m = bqm % MH;
  int q = (bqm / MH) & 1023;
  int b = bqm / (MH * 1024);
  int d = threadIdx.x;
  const int Hs[3] = {64, 32, 16};
  const int Ss[3] = {0, 4096, 5120};
  float refx = ((q & 31) + 0.5f) * (1.0f / 32.0f);
  float refy = ((q >> 5) + 0.5f) * (1.0f / 32.0f);
  const float* op = offs + ((size_t)(b * 1024 + q) * MH + m) * 24;
  const float* ap = aw + ((size_t)(b * 1024 + q) * MH + m) * 12;
  const float* vb = v + (size_t)b * 5376 * CD + m * DH + d;
  float acc = 0.0f;
#pragma unroll
  for (int l = 0; l < 3; ++l) {
    int H = Hs[l];
    float fH = (float)H;
    const float* vl = vb + (size_t)Ss[l] * CD;
#pragma unroll
    for (int p = 0; p < 4; ++p) {
      float ox = op[(l * 4 + p) * 2 + 0];
      float oy = op[(l * 4 + p) * 2 + 1];
      float xx = refx * fH + ox - 0.5f;
      float yy = refy * fH + oy - 0.5f;
      float x0f = floorf(xx), y0f = floorf(yy);
      float wx = xx - x0f, wy = yy - y0f;
      int x0 = (int)x0f, y0 = (int)y0f;
      int x1 = x0 + 1, y1 = y0 + 1;
      float sv = 0.0f;
      bool vx0 = (x0 >= 0) & (x0 < H), vx1 = (x1 >= 0) & (x1 < H);
      bool vy0 = (y0 >= 0) & (y0 < H), vy1 = (y1 >= 0) & (y1 < H);
      if (vy0) {
        if (vx0) sv += (1.0f - wx) * (1.0f - wy) * vl[(size_t)(y0 * H + x0) * CD];
        if (vx1) sv += wx * (1.0f - wy) * vl[(size_t)(y0 * H + x1) * CD];
      }
      if (vy1) {
        if (vx0) sv += (1.0f - wx) * wy * vl[(size_t)(y1 * H + x0) * CD];
        if (vx1) sv += wx * wy * vl[(size_t)(y1 * H + x1) * CD];
      }
      acc += ap[l * 4 + p] * sv;
    }
  }
  out[(size_t)(b * 1024 + q) * CD + m * DH + d] = acc;
}

// -------------------- Extractor sampling: queries=pyramid 5376, kv=ViT 32x32 ----------------
// v: (B,1024,768); offs: (B,5376,6,1,4,2); aw: (B,5376,6,4); out: (B,5376,768)
__global__ __launch_bounds__(128) void sample_ext(const float* __restrict__ v,
                                                  const float* __restrict__ offs,
                                                  const float* __restrict__ aw,
                                                  float* __restrict__ out) {
  int bqm = blockIdx.x;
  int m = bqm % MH;
  int q = (bqm / MH) % 5376;
  int b = bqm / (MH * 5376);
  int d = threadIdx.x;
  float refx, refy;
  if (q < 4096) {
    int li = q;
    refx = ((li & 63) + 0.5f) * (1.0f / 64.0f);
    refy = ((li >> 6) + 0.5f) * (1.0f / 64.0f);
  } else if (q < 5120) {
    int li = q - 4096;
    refx = ((li & 31) + 0.5f) * (1.0f / 32.0f);
    refy = ((li >> 5) + 0.5f) * (1.0f / 32.0f);
  } else {
    int li = q - 5120;
    refx = ((li & 15) + 0.5f) * (1.0f / 16.0f);
    refy = ((li >> 4) + 0.5f) * (1.0f / 16.0f);
  }
  const float* op = offs + ((size_t)(b * 5376 + q) * MH + m) * 8;
  const float* ap = aw + ((size_t)(b * 5376 + q) * MH + m) * 4;
  const float* vb = v + (size_t)b * 1024 * CD + m * DH + d;
  const int H = 32;
  float acc = 0.0f;
#pragma unroll
  for (int p = 0; p < 4; ++p) {
    float ox = op[p * 2 + 0];
    float oy = op[p * 2 + 1];
    float xx = refx * 32.0f + ox - 0.5f;
    float yy = refy * 32.0f + oy - 0.5f;
    float x0f = floorf(xx), y0f = floorf(yy);
    float wx = xx - x0f, wy = yy - y0f;
    int x0 = (int)x0f, y0 = (int)y0f;
    int x1 = x0 + 1, y1 = y0 + 1;
    float sv = 0.0f;
    bool vx0 = (x0 >= 0) & (x0 < H), vx1 = (x1 >= 0) & (x1 < H);
    bool vy0 = (y0 >= 0) & (y0 < H), vy1 = (y1 >= 0) & (y1 < H);
    if (vy0) {
      if (vx0) sv += (1.0f - wx) * (1.0f - wy) * vb[(size_t)(y0 * H + x0) * CD];
      if (vx1) sv += wx * (1.0f - wy) * vb[(size_t)(y0 * H + x1) * CD];
    }
    if (vy1) {
      if (vx0) sv += (1.0f - wx) * wy * vb[(size_t)(y1 * H + x0) * CD];
      if (vx1) sv += wx * wy * vb[(size_t)(y1 * H + x1) * CD];
    }
    acc += ap[p] * sv;
  }
  out[(size_t)(b * 5376 + q) * CD + m * DH + d] = acc;
}

// -------------------- depthwise 3x3 (per pyramid level) + bias + exact GELU -----------------
// h: (B,5376,192) channel-inner; w: (192,1,3,3); out: (B,5376,192)
__global__ __launch_bounds__(192) void dwconv_gelu(const float* __restrict__ h,
                                                   const float* __restrict__ w,
                                                   const float* __restrict__ bias,
                                                   float* __restrict__ out) {
  int bt = blockIdx.x;
  int tok = bt % 5376;
  int b = bt / 5376;
  int c = threadIdx.x;
  int H, s, li;
  if (tok < 4096) { H = 64; s = 0; li = tok; }
  else if (tok < 5120) { H = 32; s = 4096; li = tok - 4096; }
  else { H = 16; s = 5120; li = tok - 5120; }
  int y = li / H, x = li % H;
  const float* hb = h + ((size_t)b * 5376 + s) * 192 + c;
  float acc = 0.0f;
#pragma unroll
  for (int dy = -1; dy <= 1; ++dy) {
    int yy = y + dy;
    if (yy < 0 || yy >= H) continue;
#pragma unroll
    for (int dx = -1; dx <= 1; ++dx) {
      int xx = x + dx;
      if (xx < 0 || xx >= H) continue;
      acc += w[c * 9 + (dy + 1) * 3 + (dx + 1)] * hb[(size_t)(yy * H + xx) * 192];
    }
  }
  acc += bias[c];
  float g = 0.5f * acc * (1.0f + erff(acc * 0.70710678118654752f));
  out[((size_t)b * 5376 + tok) * 192 + c] = g;
}

// -------------------- host launcher --------------------
extern "C" void kernel_launch(void* const* d_in, const int* in_sizes, int n_in,
                              void* d_out, int out_size, void* d_ws, size_t ws_size,
                              hipStream_t stream) {
  (void)in_sizes; (void)n_in; (void)out_size; (void)ws_size;
  const float* x        = (const float*)d_in[0];
  const float* c        = (const float*)d_in[1];
  const float* inj_n1g  = (const float*)d_in[2];
  const float* inj_n1b  = (const float*)d_in[3];
  const float* inj_n2g  = (const float*)d_in[4];
  const float* inj_n2b  = (const float*)d_in[5];
  const float* inj_off_w = (const float*)d_in[6];
  const float* inj_off_b = (const float*)d_in[7];
  const float* inj_aw_w = (const float*)d_in[8];
  const float* inj_aw_b = (const float*)d_in[9];
  const float* inj_val_w = (const float*)d_in[10];
  const float* inj_val_b = (const float*)d_in[11];
  const float* inj_out_w = (const float*)d_in[12];
  const float* inj_out_b = (const float*)d_in[13];
  const float* ext_n1g  = (const float*)d_in[14];
  const float* ext_n1b  = (const float*)d_in[15];
  const float* ext_n2g  = (const float*)d_in[16];
  const float* ext_n2b  = (const float*)d_in[17];
  const float* ext_off_w = (const float*)d_in[18];
  const float* ext_off_b = (const float*)d_in[19];
  const float* ext_aw_w = (const float*)d_in[20];
  const float* ext_aw_b = (const float*)d_in[21];
  const float* ext_val_w = (const float*)d_in[22];
  const float* ext_val_b = (const float*)d_in[23];
  const float* ext_out_w = (const float*)d_in[24];
  const float* ext_out_b = (const float*)d_in[25];
  const float* inj_gamma = (const float*)d_in[26];
  const float* ext_ng   = (const float*)d_in[27];
  const float* ext_nb   = (const float*)d_in[28];
  const float* ext_fc1_w = (const float*)d_in[29];
  const float* ext_fc1_b = (const float*)d_in[30];
  const float* ext_dw_w = (const float*)d_in[31];
  const float* ext_dw_b = (const float*)d_in[32];
  const float* ext_fc2_w = (const float*)d_in[33];
  const float* ext_fc2_b = (const float*)d_in[34];

  const int Sx = 4096;     // B*1024 rows
  const int Sc = 21504;    // B*5376 rows
  float* xout = (float*)d_out;                       // (4,1024,768)
  float* cout = (float*)d_out + (size_t)Sx * CD;     // (4,5376,768)

  float* ws = (float*)d_ws;
  const size_t BIG = (size_t)Sc * CD;      // 16,515,072
  const size_t SMALL = (size_t)Sx * CD;    // 3,145,728
  float* big1 = ws;                        // LN(c) buffers / qc / LN(c1)
  float* big2 = big1 + BIG;                // v_inj / attn_ext
  float* small1 = big2 + BIG;              // qx / LN(x_new)
  float* small2 = small1 + SMALL;          // attn_inj / v_ext
  float* offsb = small2 + SMALL;           // max(4096*144, 21504*48) = 1,032,192
  float* awb = offsb + 1032192;            // max(4096*72, 21504*24) = 516,096
  float* hbuf = awb + 516096;              // 21504*192
  float* h2buf = hbuf + (size_t)Sc * 192;  // 21504*192

  // ---------------- Phase 1: Injector ----------------
  ln_kernel<<<Sx, 256, 0, stream>>>(x, inj_n1g, inj_n1b, small1);
  ln_kernel<<<Sc, 256, 0, stream>>>(c, inj_n2g, inj_n2b, big1);
  gemm128<0><<<dim3(6, Sc / 128), 256, 0, stream>>>(big1, inj_val_w, inj_val_b, nullptr, nullptr, big2, Sc, CD, CD);
  gemm128<0><<<dim3(2, Sx / 128), 256, 0, stream>>>(small1, inj_off_w, inj_off_b, nullptr, nullptr, offsb, Sx, 144, CD);
  gemm128<0><<<dim3(1, Sx / 128), 256, 0, stream>>>(small1, inj_aw_w, inj_aw_b, nullptr, nullptr, awb, Sx, 72, CD);
  softmax_lp<<<(Sx * MH + 255) / 256, 256, 0, stream>>>(awb, Sx * MH, 12);
  sample_inj<<<Sx * MH, 128, 0, stream>>>(big2, offsb, awb, small2);
  gemm128<1><<<dim3(6, Sx / 128), 256, 0, stream>>>(small2, inj_out_w, inj_out_b, x, inj_gamma, xout, Sx, CD, CD);

  // ---------------- Phase 2: Extractor ----------------
  ln_kernel<<<Sc, 256, 0, stream>>>(c, ext_n1g, ext_n1b, big1);
  ln_kernel<<<Sx, 256, 0, stream>>>(xout, ext_n2g, ext_n2b, small1);
  gemm128<0><<<dim3(6, Sx / 128), 256, 0, stream>>>(small1, ext_val_w, ext_val_b, nullptr, nullptr, small2, Sx, CD, CD);
  gemm128<0><<<dim3(1, Sc / 128), 256, 0, stream>>>(big1, ext_off_w, ext_off_b, nullptr, nullptr, offsb, Sc, 48, CD);
  gemm128<0><<<dim3(1, Sc / 128), 256, 0, stream>>>(big1, ext_aw_w, ext_aw_b, nullptr, nullptr, awb, Sc, 24, CD);
  softmax_lp<<<(Sc * MH + 255) / 256, 256, 0, stream>>>(awb, Sc * MH, 4);
  sample_ext<<<Sc * MH, 128, 0, stream>>>(small2, offsb, awb, big2);
  gemm128<2><<<dim3(6, Sc / 128), 256, 0, stream>>>(big2, ext_out_w, ext_out_b, c, nullptr, cout, Sc, CD, CD);

  // ---------------- Phase 3: ConvFFN ----------------
  ln_kernel<<<Sc, 256, 0, stream>>>(cout, ext_ng, ext_nb, big1);
  gemm128<0><<<dim3(2, Sc / 128), 256, 0, stream>>>(big1, ext_fc1_w, ext_fc1_b, nullptr, nullptr, hbuf, Sc, 192, CD);
  dwconv_gelu<<<Sc, 192, 0, stream>>>(hbuf, ext_dw_w, ext_dw_b, h2buf);
  gemm128<2><<<dim3(6, Sc / 128), 256, 0, stream>>>(h2buf, ext_fc2_w, ext_fc2_b, cout, nullptr, cout, Sc, CD, 192);
}

// Round 4
// 954.262 us; speedup vs baseline: 2.0945x; 2.0945x over previous
//
#include <hip/hip_runtime.h>
#include <math.h>
#include <stdint.h>

#define CD 768
#define DH 128
#define MH 6

using half_t = _Float16;
typedef __attribute__((ext_vector_type(8))) _Float16 f16x8;
typedef __attribute__((ext_vector_type(4))) float f32x4;

// -------------------- async global->LDS (16B per lane, wave-uniform LDS base) ---------------
__device__ __forceinline__ void gload16(const half_t* g, half_t* l) {
  __builtin_amdgcn_global_load_lds((__attribute__((address_space(1))) void*)g,
                                   (__attribute__((address_space(3))) void*)l, 16, 0, 0);
}

// -------------------- wave reduction --------------------
static __device__ __forceinline__ float wred(float v) {
#pragma unroll
  for (int off = 32; off > 0; off >>= 1) v += __shfl_down(v, off, 64);
  return v;
}

// -------------------- LayerNorm (fp32 in, fp16 out): one block per row of 768 ---------------
__global__ __launch_bounds__(256) void ln_f16(const float* __restrict__ in,
                                              const float* __restrict__ g,
                                              const float* __restrict__ b,
                                              half_t* __restrict__ out) {
  int row = blockIdx.x;
  const float* xp = in + (size_t)row * CD;
  half_t* op = out + (size_t)row * CD;
  int t = threadIdx.x;
  float v0 = xp[t], v1 = xp[t + 256], v2 = xp[t + 512];
  __shared__ float wsum[4];
  __shared__ float stat[2];
  int wid = t >> 6, lane = t & 63;
  float s = wred(v0 + v1 + v2);
  if (lane == 0) wsum[wid] = s;
  __syncthreads();
  if (t == 0) stat[0] = (wsum[0] + wsum[1] + wsum[2] + wsum[3]) * (1.0f / 768.0f);
  __syncthreads();
  float mu = stat[0];
  float d0 = v0 - mu, d1 = v1 - mu, d2 = v2 - mu;
  float q = wred(d0 * d0 + d1 * d1 + d2 * d2);
  if (lane == 0) wsum[wid] = q;
  __syncthreads();
  if (t == 0) {
    float var = (wsum[0] + wsum[1] + wsum[2] + wsum[3]) * (1.0f / 768.0f);
    stat[1] = 1.0f / sqrtf(var + 1e-6f);
  }
  __syncthreads();
  float rstd = stat[1];
  op[t]       = (half_t)(d0 * rstd * g[t]       + b[t]);
  op[t + 256] = (half_t)(d1 * rstd * g[t + 256] + b[t + 256]);
  op[t + 512] = (half_t)(d2 * rstd * g[t + 512] + b[t + 512]);
}

// -------------------- weight convert: fp32 (K,N) -> fp16 (Npad,K) transposed, zero-padded ---
__global__ __launch_bounds__(256) void convert_w(const float* __restrict__ W,
                                                 half_t* __restrict__ Wt,
                                                 int K, int N, int total) {
  int idx = blockIdx.x * blockDim.x + threadIdx.x;
  if (idx >= total) return;
  int n = idx / K, k = idx - n * K;
  Wt[idx] = (n < N) ? (half_t)W[(size_t)k * N + n] : (half_t)0.0f;
}

// -------------------- MFMA fp16 GEMM: out = epilogue(A @ Wt^T + bias) -----------------------
// A: (M,K) fp16 row-major. Wt: (Npad,K) fp16 row-major (= W^T, zero-padded cols).
// out row stride = N. MODE 0: acc+bias; 1: res + gamma*(acc+bias); 2: res + acc+bias.
// M%128==0, K%32==0, grid = (Npad/128, M/128), 256 threads.
template <int MODE, int OUTF16>
__global__ __launch_bounds__(256) void gemm_mfma(const half_t* __restrict__ A,
                                                 const half_t* __restrict__ Wt,
                                                 const float* __restrict__ bias,
                                                 const float* __restrict__ res,
                                                 const float* __restrict__ gamma,
                                                 void* __restrict__ outv,
                                                 int M, int N, int K) {
  __shared__ half_t smem[8192];  // As [128][32] at 0, Bs [128][32] at 4096 (halves)
  const int tid = threadIdx.x;
  const int w = tid >> 6;
  const int l = tid & 63;
  const int wr = w >> 1, wc = w & 1;
  const int bm = blockIdx.y * 128;
  const int bn = blockIdx.x * 128;

  f32x4 acc[4][4];
#pragma unroll
  for (int i = 0; i < 4; ++i)
#pragma unroll
    for (int j = 0; j < 4; ++j) acc[i][j] = (f32x4){0.f, 0.f, 0.f, 0.f};

  // staging: issue j in {2w, 2w+1}; lane covers row j*16+(l>>2), col (l&3)*8 -> lds lin l*16B
  const int j0 = w * 2;
  const int sr = l >> 2;
  const int sc = (l & 3) * 8;
  const half_t* Ag0 = A + (size_t)(bm + j0 * 16 + sr) * K + sc;
  const half_t* Ag1 = Ag0 + (size_t)16 * K;
  const half_t* Bg0 = Wt + (size_t)(bn + j0 * 16 + sr) * K + sc;
  const half_t* Bg1 = Bg0 + (size_t)16 * K;
  half_t* As0 = smem + j0 * 512;
  half_t* As1 = As0 + 512;
  half_t* Bs0 = smem + 4096 + j0 * 512;
  half_t* Bs1 = Bs0 + 512;

  const int fr = l & 15;
  const int fk = (l >> 4) * 8;
  const int abase = (wr * 64 + fr) * 32 + fk;
  const int bbase = 4096 + (wc * 64 + fr) * 32 + fk;

  for (int k0 = 0; k0 < K; k0 += 32) {
    gload16(Ag0 + k0, As0);
    gload16(Ag1 + k0, As1);
    gload16(Bg0 + k0, Bs0);
    gload16(Bg1 + k0, Bs1);
    __syncthreads();  // drains vmcnt -> staged data visible
    f16x8 af[4], bf[4];
#pragma unroll
    for (int i = 0; i < 4; ++i) {
      af[i] = *(const f16x8*)&smem[abase + i * 512];
      bf[i] = *(const f16x8*)&smem[bbase + i * 512];
    }
#pragma unroll
    for (int i = 0; i < 4; ++i)
#pragma unroll
      for (int j = 0; j < 4; ++j)
        acc[i][j] = __builtin_amdgcn_mfma_f32_16x16x32_f16(af[i], bf[j], acc[i][j], 0, 0, 0);
    __syncthreads();  // LDS reuse guard
  }

  // epilogue: D elem (row=(l>>4)*4+r, col=l&15) per 16x16 fragment [m89-verified]
#pragma unroll
  for (int i = 0; i < 4; ++i) {
    int row0 = bm + wr * 64 + i * 16 + (l >> 4) * 4;
#pragma unroll
    for (int r = 0; r < 4; ++r) {
      size_t rowoff = (size_t)(row0 + r) * N;
#pragma unroll
      for (int j = 0; j < 4; ++j) {
        int col = bn + wc * 64 + j * 16 + fr;
        if (col < N) {
          float v = acc[i][j][r] + bias[col];
          if (MODE == 1) v = res[rowoff + col] + gamma[col] * v;
          else if (MODE == 2) v = res[rowoff + col] + v;
          if (OUTF16) ((half_t*)outv)[rowoff + col] = (half_t)v;
          else ((float*)outv)[rowoff + col] = v;
        }
      }
    }
  }
}

// -------------------- softmax over last LP entries, one thread per (b,q,m) ------------------
__global__ void softmax_lp(float* __restrict__ a, int total, int LP) {
  int i = blockIdx.x * blockDim.x + threadIdx.x;
  if (i >= total) return;
  float* p = a + (size_t)i * LP;
  float mx = -1e30f;
  for (int j = 0; j < LP; ++j) mx = fmaxf(mx, p[j]);
  float s = 0.0f;
  for (int j = 0; j < LP; ++j) {
    float e = expf(p[j] - mx);
    p[j] = e;
    s += e;
  }
  float inv = 1.0f / s;
  for (int j = 0; j < LP; ++j) p[j] *= inv;
}

// -------------------- Injector sampling: queries=ViT 32x32, kv=pyramid (3 levels) -----------
__global__ __launch_bounds__(128) void sample_inj(const half_t* __restrict__ v,
                                                  const float* __restrict__ offs,
                                                  const float* __restrict__ aw,
                                                  half_t* __restrict__ out) {
  int bqm = blockIdx.x;
  int m = bqm % MH;
  int q = (bqm / MH) & 1023;
  int b = bqm / (MH * 1024);
  int d = threadIdx.x;
  const int Hs[3] = {64, 32, 16};
  const int Ss[3] = {0, 4096, 5120};
  float refx = ((q & 31) + 0.5f) * (1.0f / 32.0f);
  float refy = ((q >> 5) + 0.5f) * (1.0f / 32.0f);
  const float* op = offs + ((size_t)(b * 1024 + q) * MH + m) * 24;
  const float* ap = aw + ((size_t)(b * 1024 + q) * MH + m) * 12;
  const half_t* vb = v + (size_t)b * 5376 * CD + m * DH + d;
  float acc = 0.0f;
#pragma unroll
  for (int l = 0; l < 3; ++l) {
    int H = Hs[l];
    float fH = (float)H;
    const half_t* vl = vb + (size_t)Ss[l] * CD;
#pragma unroll
    for (int p = 0; p < 4; ++p) {
      float ox = op[(l * 4 + p) * 2 + 0];
      float oy = op[(l * 4 + p) * 2 + 1];
      float xx = refx * fH + ox - 0.5f;
      float yy = refy * fH + oy - 0.5f;
      float x0f = floorf(xx), y0f = floorf(yy);
      float wx = xx - x0f, wy = yy - y0f;
      int x0 = (int)x0f, y0 = (int)y0f;
      int x1 = x0 + 1, y1 = y0 + 1;
      float sv = 0.0f;
      bool vx0 = (x0 >= 0) & (x0 < H), vx1 = (x1 >= 0) & (x1 < H);
      bool vy0 = (y0 >= 0) & (y0 < H), vy1 = (y1 >= 0) & (y1 < H);
      if (vy0) {
        if (vx0) sv += (1.0f - wx) * (1.0f - wy) * (float)vl[(size_t)(y0 * H + x0) * CD];
        if (vx1) sv += wx * (1.0f - wy) * (float)vl[(size_t)(y0 * H + x1) * CD];
      }
      if (vy1) {
        if (vx0) sv += (1.0f - wx) * wy * (float)vl[(size_t)(y1 * H + x0) * CD];
        if (vx1) sv += wx * wy * (float)vl[(size_t)(y1 * H + x1) * CD];
      }
      acc += ap[l * 4 + p] * sv;
    }
  }
  out[(size_t)(b * 1024 + q) * CD + m * DH + d] = (half_t)acc;
}

// -------------------- Extractor sampling: queries=pyramid 5376, kv=ViT 32x32 ----------------
__global__ __launch_bounds__(128) void sample_ext(const half_t* __restrict__ v,
                                                  const float* __restrict__ offs,
                                                  const float* __restrict__ aw,
                                                  half_t* __restrict__ out) {
  int bqm = blockIdx.x;
  int m = bqm % MH;
  int q = (bqm / MH) % 5376;
  int b = bqm / (MH * 5376);
  int d = threadIdx.x;
  float refx, refy;
  if (q < 4096) {
    int li = q;
    refx = ((li & 63) + 0.5f) * (1.0f / 64.0f);
    refy = ((li >> 6) + 0.5f) * (1.0f / 64.0f);
  } else if (q < 5120) {
    int li = q - 4096;
    refx = ((li & 31) + 0.5f) * (1.0f / 32.0f);
    refy = ((li >> 5) + 0.5f) * (1.0f / 32.0f);
  } else {
    int li = q - 5120;
    refx = ((li & 15) + 0.5f) * (1.0f / 16.0f);
    refy = ((li >> 4) + 0.5f) * (1.0f / 16.0f);
  }
  const float* op = offs + ((size_t)(b * 5376 + q) * MH + m) * 8;
  const float* ap = aw + ((size_t)(b * 5376 + q) * MH + m) * 4;
  const half_t* vb = v + (size_t)b * 1024 * CD + m * DH + d;
  const int H = 32;
  float acc = 0.0f;
#pragma unroll
  for (int p = 0; p < 4; ++p) {
    float ox = op[p * 2 + 0];
    float oy = op[p * 2 + 1];
    float xx = refx * 32.0f + ox - 0.5f;
    float yy = refy * 32.0f + oy - 0.5f;
    float x0f = floorf(xx), y0f = floorf(yy);
    float wx = xx - x0f, wy = yy - y0f;
    int x0 = (int)x0f, y0 = (int)y0f;
    int x1 = x0 + 1, y1 = y0 + 1;
    float sv = 0.0f;
    bool vx0 = (x0 >= 0) & (x0 < H), vx1 = (x1 >= 0) & (x1 < H);
    bool vy0 = (y0 >= 0) & (y0 < H), vy1 = (y1 >= 0) & (y1 < H);
    if (vy0) {
      if (vx0) sv += (1.0f - wx) * (1.0f - wy) * (float)vb[(size_t)(y0 * H + x0) * CD];
      if (vx1) sv += wx * (1.0f - wy) * (float)vb[(size_t)(y0 * H + x1) * CD];
    }
    if (vy1) {
      if (vx0) sv += (1.0f - wx) * wy * (float)vb[(size_t)(y1 * H + x0) * CD];
      if (vx1) sv += wx * wy * (float)vb[(size_t)(y1 * H + x1) * CD];
    }
    acc += ap[p] * sv;
  }
  out[(size_t)(b * 5376 + q) * CD + m * DH + d] = (half_t)acc;
}

// -------------------- depthwise 3x3 + bias + exact GELU (fp16 in/out) -----------------------
__global__ __launch_bounds__(192) void dwconv_gelu(const half_t* __restrict__ h,
                                                   const float* __restrict__ w,
                                                   const float* __restrict__ bias,
                                                   half_t* __restrict__ out) {
  int bt = blockIdx.x;
  int tok = bt % 5376;
  int b = bt / 5376;
  int c = threadIdx.x;
  int H, s, li;
  if (tok < 4096) { H = 64; s = 0; li = tok; }
  else if (tok < 5120) { H = 32; s = 4096; li = tok - 4096; }
  else { H = 16; s = 5120; li = tok - 5120; }
  int y = li / H, x = li % H;
  const half_t* hb = h + ((size_t)b * 5376 + s) * 192 + c;
  float acc = 0.0f;
#pragma unroll
  for (int dy = -1; dy <= 1; ++dy) {
    int yy = y + dy;
    if (yy < 0 || yy >= H) continue;
#pragma unroll
    for (int dx = -1; dx <= 1; ++dx) {
      int xx = x + dx;
      if (xx < 0 || xx >= H) continue;
      acc += w[c * 9 + (dy + 1) * 3 + (dx + 1)] * (float)hb[(size_t)(yy * H + xx) * 192];
    }
  }
  acc += bias[c];
  float g = 0.5f * acc * (1.0f + erff(acc * 0.70710678118654752f));
  out[((size_t)b * 5376 + tok) * 192 + c] = (half_t)g;
}

// -------------------- host launcher --------------------
extern "C" void kernel_launch(void* const* d_in, const int* in_sizes, int n_in,
                              void* d_out, int out_size, void* d_ws, size_t ws_size,
                              hipStream_t stream) {
  (void)in_sizes; (void)n_in; (void)out_size; (void)ws_size;
  const float* x        = (const float*)d_in[0];
  const float* c        = (const float*)d_in[1];
  const float* inj_n1g  = (const float*)d_in[2];
  const float* inj_n1b  = (const float*)d_in[3];
  const float* inj_n2g  = (const float*)d_in[4];
  const float* inj_n2b  = (const float*)d_in[5];
  const float* inj_off_w = (const float*)d_in[6];
  const float* inj_off_b = (const float*)d_in[7];
  const float* inj_aw_w = (const float*)d_in[8];
  const float* inj_aw_b = (const float*)d_in[9];
  const float* inj_val_w = (const float*)d_in[10];
  const float* inj_val_b = (const float*)d_in[11];
  const float* inj_out_w = (const float*)d_in[12];
  const float* inj_out_b = (const float*)d_in[13];
  const float* ext_n1g  = (const float*)d_in[14];
  const float* ext_n1b  = (const float*)d_in[15];
  const float* ext_n2g  = (const float*)d_in[16];
  const float* ext_n2b  = (const float*)d_in[17];
  const float* ext_off_w = (const float*)d_in[18];
  const float* ext_off_b = (const float*)d_in[19];
  const float* ext_aw_w = (const float*)d_in[20];
  const float* ext_aw_b = (const float*)d_in[21];
  const float* ext_val_w = (const float*)d_in[22];
  const float* ext_val_b = (const float*)d_in[23];
  const float* ext_out_w = (const float*)d_in[24];
  const float* ext_out_b = (const float*)d_in[25];
  const float* inj_gamma = (const float*)d_in[26];
  const float* ext_ng   = (const float*)d_in[27];
  const float* ext_nb   = (const float*)d_in[28];
  const float* ext_fc1_w = (const float*)d_in[29];
  const float* ext_fc1_b = (const float*)d_in[30];
  const float* ext_dw_w = (const float*)d_in[31];
  const float* ext_dw_b = (const float*)d_in[32];
  const float* ext_fc2_w = (const float*)d_in[33];
  const float* ext_fc2_b = (const float*)d_in[34];

  const int Sx = 4096;   // B*1024
  const int Sc = 21504;  // B*5376
  float* xout = (float*)d_out;
  float* cout = (float*)d_out + (size_t)Sx * CD;

  // ---- workspace layout (halves then floats), ~108 MB total ----
  half_t* bigA   = (half_t*)d_ws;           // 16,515,072 h  LN(c)/LN(cout)
  half_t* bigV   = bigA + 16515072;         // 16,515,072 h  v_inj / attn_ext
  half_t* smallA = bigV + 16515072;         //  3,145,728 h  LN(x)/LN(xout)
  half_t* smallB = smallA + 3145728;        //  3,145,728 h  attn_inj / v_ext
  half_t* h16    = smallB + 3145728;        //  4,128,768 h  fc1 out
  half_t* h2     = h16 + 4128768;           //  4,128,768 h  dwconv out
  half_t* w_inj_val = h2 + 4128768;         // 589,824
  half_t* w_inj_out = w_inj_val + 589824;   // 589,824
  half_t* w_ext_val = w_inj_out + 589824;   // 589,824
  half_t* w_ext_out = w_ext_val + 589824;   // 589,824
  half_t* w_fc2     = w_ext_out + 589824;   // 147,456 (768 x 192)
  half_t* w_inj_off = w_fc2 + 147456;       // 196,608 (256 x 768)
  half_t* w_inj_aw  = w_inj_off + 196608;   //  98,304 (128 x 768)
  half_t* w_ext_off = w_inj_aw + 98304;     //  98,304
  half_t* w_ext_aw  = w_ext_off + 98304;    //  98,304
  half_t* w_fc1     = w_ext_aw + 98304;     // 196,608 (256 x 768)
  float* offsb = (float*)(((uintptr_t)(w_fc1 + 196608) + 255) & ~(uintptr_t)255);
  float* awb = offsb + 1032192;

  auto conv = [&](const float* W, half_t* Wt, int K, int N, int Npad) {
    int total = Npad * K;
    convert_w<<<(total + 255) / 256, 256, 0, stream>>>(W, Wt, K, N, total);
  };
  conv(inj_val_w, w_inj_val, 768, 768, 768);
  conv(inj_off_w, w_inj_off, 768, 144, 256);
  conv(inj_aw_w,  w_inj_aw,  768, 72, 128);
  conv(inj_out_w, w_inj_out, 768, 768, 768);
  conv(ext_val_w, w_ext_val, 768, 768, 768);
  conv(ext_off_w, w_ext_off, 768, 48, 128);
  conv(ext_aw_w,  w_ext_aw,  768, 24, 128);
  conv(ext_out_w, w_ext_out, 768, 768, 768);
  conv(ext_fc1_w, w_fc1, 768, 192, 256);
  conv(ext_fc2_w, w_fc2, 192, 768, 768);

  // ---------------- Phase 1: Injector ----------------
  ln_f16<<<Sx, 256, 0, stream>>>(x, inj_n1g, inj_n1b, smallA);
  ln_f16<<<Sc, 256, 0, stream>>>(c, inj_n2g, inj_n2b, bigA);
  gemm_mfma<0, 1><<<dim3(6, 168), 256, 0, stream>>>(bigA, w_inj_val, inj_val_b, nullptr, nullptr, bigV, Sc, 768, 768);
  gemm_mfma<0, 0><<<dim3(2, 32), 256, 0, stream>>>(smallA, w_inj_off, inj_off_b, nullptr, nullptr, offsb, Sx, 144, 768);
  gemm_mfma<0, 0><<<dim3(1, 32), 256, 0, stream>>>(smallA, w_inj_aw, inj_aw_b, nullptr, nullptr, awb, Sx, 72, 768);
  softmax_lp<<<(Sx * MH + 255) / 256, 256, 0, stream>>>(awb, Sx * MH, 12);
  sample_inj<<<Sx * MH, 128, 0, stream>>>(bigV, offsb, awb, smallB);
  gemm_mfma<1, 0><<<dim3(6, 32), 256, 0, stream>>>(smallB, w_inj_out, inj_out_b, x, inj_gamma, xout, Sx, 768, 768);

  // ---------------- Phase 2: Extractor ----------------
  ln_f16<<<Sc, 256, 0, stream>>>(c, ext_n1g, ext_n1b, bigA);
  ln_f16<<<Sx, 256, 0, stream>>>(xout, ext_n2g, ext_n2b, smallA);
  gemm_mfma<0, 1><<<dim3(6, 32), 256, 0, stream>>>(smallA, w_ext_val, ext_val_b, nullptr, nullptr, smallB, Sx, 768, 768);
  gemm_mfma<0, 0><<<dim3(1, 168), 256, 0, stream>>>(bigA, w_ext_off, ext_off_b, nullptr, nullptr, offsb, Sc, 48, 768);
  gemm_mfma<0, 0><<<dim3(1, 168), 256, 0, stream>>>(bigA, w_ext_aw, ext_aw_b, nullptr, nullptr, awb, Sc, 24, 768);
  softmax_lp<<<(Sc * MH + 255) / 256, 256, 0, stream>>>(awb, Sc * MH, 4);
  sample_ext<<<Sc * MH, 128, 0, stream>>>(smallB, offsb, awb, bigV);
  gemm_mfma<2, 0><<<dim3(6, 168), 256, 0, stream>>>(bigV, w_ext_out, ext_out_b, c, nullptr, cout, Sc, 768, 768);

  // ---------------- Phase 3: ConvFFN ----------------
  ln_f16<<<Sc, 256, 0, stream>>>(cout, ext_ng, ext_nb, bigA);
  gemm_mfma<0, 1><<<dim3(2, 168), 256, 0, stream>>>(bigA, w_fc1, ext_fc1_b, nullptr, nullptr, h16, Sc, 192, 768);
  dwconv_gelu<<<Sc, 192, 0, stream>>>(h16, ext_dw_w, ext_dw_b, h2);
  gemm_mfma<2, 0><<<dim3(6, 168), 256, 0, stream>>>(h2, w_fc2, ext_fc2_b, cout, nullptr, cout, Sc, 768, 192);
}

// Round 5
// 780.038 us; speedup vs baseline: 2.5623x; 1.2234x over previous
//
#include <hip/hip_runtime.h>
#include <math.h>
#include <stdint.h>

#define CD 768
#define DH 128
#define MH 6

using half_t = _Float16;
typedef __attribute__((ext_vector_type(8))) _Float16 f16x8;
typedef __attribute__((ext_vector_type(4))) float f32x4;

// -------------------- async global->LDS (16B per lane, wave-uniform LDS base) ---------------
__device__ __forceinline__ void gload16(const half_t* g, half_t* l) {
  __builtin_amdgcn_global_load_lds((__attribute__((address_space(1))) void*)g,
                                   (__attribute__((address_space(3))) void*)l, 16, 0, 0);
}

// -------------------- wave reduction --------------------
static __device__ __forceinline__ float wred(float v) {
#pragma unroll
  for (int off = 32; off > 0; off >>= 1) v += __shfl_down(v, off, 64);
  return v;
}

// -------------------- LayerNorm (fp32 in, fp16 out): one block per row of 768 ---------------
__global__ __launch_bounds__(256) void ln_f16(const float* __restrict__ in,
                                              const float* __restrict__ g,
                                              const float* __restrict__ b,
                                              half_t* __restrict__ out) {
  int row = blockIdx.x;
  const float* xp = in + (size_t)row * CD;
  half_t* op = out + (size_t)row * CD;
  int t = threadIdx.x;
  float v0 = xp[t], v1 = xp[t + 256], v2 = xp[t + 512];
  __shared__ float wsum[4];
  __shared__ float stat[2];
  int wid = t >> 6, lane = t & 63;
  float s = wred(v0 + v1 + v2);
  if (lane == 0) wsum[wid] = s;
  __syncthreads();
  if (t == 0) stat[0] = (wsum[0] + wsum[1] + wsum[2] + wsum[3]) * (1.0f / 768.0f);
  __syncthreads();
  float mu = stat[0];
  float d0 = v0 - mu, d1 = v1 - mu, d2 = v2 - mu;
  float q = wred(d0 * d0 + d1 * d1 + d2 * d2);
  if (lane == 0) wsum[wid] = q;
  __syncthreads();
  if (t == 0) {
    float var = (wsum[0] + wsum[1] + wsum[2] + wsum[3]) * (1.0f / 768.0f);
    stat[1] = 1.0f / sqrtf(var + 1e-6f);
  }
  __syncthreads();
  float rstd = stat[1];
  op[t]       = (half_t)(d0 * rstd * g[t]       + b[t]);
  op[t + 256] = (half_t)(d1 * rstd * g[t + 256] + b[t + 256]);
  op[t + 512] = (half_t)(d2 * rstd * g[t + 512] + b[t + 512]);
}

// -------------------- dual LayerNorm: same input row, two (g,b) pairs, two outputs ----------
__global__ __launch_bounds__(256) void ln_dual(const float* __restrict__ in,
                                               const float* __restrict__ g1,
                                               const float* __restrict__ b1,
                                               half_t* __restrict__ o1,
                                               const float* __restrict__ g2,
                                               const float* __restrict__ b2,
                                               half_t* __restrict__ o2) {
  int row = blockIdx.x;
  const float* xp = in + (size_t)row * CD;
  int t = threadIdx.x;
  float v0 = xp[t], v1 = xp[t + 256], v2 = xp[t + 512];
  __shared__ float wsum[4];
  __shared__ float stat[2];
  int wid = t >> 6, lane = t & 63;
  float s = wred(v0 + v1 + v2);
  if (lane == 0) wsum[wid] = s;
  __syncthreads();
  if (t == 0) stat[0] = (wsum[0] + wsum[1] + wsum[2] + wsum[3]) * (1.0f / 768.0f);
  __syncthreads();
  float mu = stat[0];
  float d0 = v0 - mu, d1 = v1 - mu, d2 = v2 - mu;
  float q = wred(d0 * d0 + d1 * d1 + d2 * d2);
  if (lane == 0) wsum[wid] = q;
  __syncthreads();
  if (t == 0) {
    float var = (wsum[0] + wsum[1] + wsum[2] + wsum[3]) * (1.0f / 768.0f);
    stat[1] = 1.0f / sqrtf(var + 1e-6f);
  }
  __syncthreads();
  float rstd = stat[1];
  half_t* p1 = o1 + (size_t)row * CD;
  half_t* p2 = o2 + (size_t)row * CD;
  float n0 = d0 * rstd, n1 = d1 * rstd, n2 = d2 * rstd;
  p1[t]       = (half_t)(n0 * g1[t]       + b1[t]);
  p1[t + 256] = (half_t)(n1 * g1[t + 256] + b1[t + 256]);
  p1[t + 512] = (half_t)(n2 * g1[t + 512] + b1[t + 512]);
  p2[t]       = (half_t)(n0 * g2[t]       + b2[t]);
  p2[t + 256] = (half_t)(n1 * g2[t + 256] + b2[t + 256]);
  p2[t + 512] = (half_t)(n2 * g2[t + 512] + b2[t + 512]);
}

// -------------------- fused weight convert: 10 segments, fp32 (K,N) -> fp16 (Npad,K) --------
struct ConvArgs {
  const float* W[10];
  half_t* Wt[10];
  int K[10];
  int N[10];
  int base[11];
};
__global__ __launch_bounds__(256) void convert_all(ConvArgs a) {
  int idx = blockIdx.x * 256 + threadIdx.x;
  if (idx >= a.base[10]) return;
  int s = 0;
  while (idx >= a.base[s + 1]) ++s;
  int local = idx - a.base[s];
  int K = a.K[s], N = a.N[s];
  int n = local / K, k = local - n * K;
  a.Wt[s][local] = (n < N) ? (half_t)a.W[s][(size_t)k * N + n] : (half_t)0.0f;
}

// -------------------- MFMA fp16 GEMM: out = epilogue(A @ Wt^T + bias) -----------------------
// A: (M,K) fp16 row-major. Wt: (Npad,K) fp16 row-major (= W^T, zero-padded cols).
// out row stride = N. MODE 0: acc+bias; 1: res + gamma*(acc+bias); 2: res + acc+bias.
// M%128==0, K%32==0, grid = (Npad/128, M/128), 256 threads.
template <int MODE, int OUTF16>
__global__ __launch_bounds__(256) void gemm_mfma(const half_t* __restrict__ A,
                                                 const half_t* __restrict__ Wt,
                                                 const float* __restrict__ bias,
                                                 const float* __restrict__ res,
                                                 const float* __restrict__ gamma,
                                                 void* __restrict__ outv,
                                                 int M, int N, int K) {
  __shared__ half_t smem[8192];  // As [128][32] at 0, Bs [128][32] at 4096 (halves)
  const int tid = threadIdx.x;
  const int w = tid >> 6;
  const int l = tid & 63;
  const int wr = w >> 1, wc = w & 1;
  const int bm = blockIdx.y * 128;
  const int bn = blockIdx.x * 128;

  f32x4 acc[4][4];
#pragma unroll
  for (int i = 0; i < 4; ++i)
#pragma unroll
    for (int j = 0; j < 4; ++j) acc[i][j] = (f32x4){0.f, 0.f, 0.f, 0.f};

  const int j0 = w * 2;
  const int sr = l >> 2;
  const int sc = (l & 3) * 8;
  const half_t* Ag0 = A + (size_t)(bm + j0 * 16 + sr) * K + sc;
  const half_t* Ag1 = Ag0 + (size_t)16 * K;
  const half_t* Bg0 = Wt + (size_t)(bn + j0 * 16 + sr) * K + sc;
  const half_t* Bg1 = Bg0 + (size_t)16 * K;
  half_t* As0 = smem + j0 * 512;
  half_t* As1 = As0 + 512;
  half_t* Bs0 = smem + 4096 + j0 * 512;
  half_t* Bs1 = Bs0 + 512;

  const int fr = l & 15;
  const int fk = (l >> 4) * 8;
  const int abase = (wr * 64 + fr) * 32 + fk;
  const int bbase = 4096 + (wc * 64 + fr) * 32 + fk;

  for (int k0 = 0; k0 < K; k0 += 32) {
    gload16(Ag0 + k0, As0);
    gload16(Ag1 + k0, As1);
    gload16(Bg0 + k0, Bs0);
    gload16(Bg1 + k0, Bs1);
    __syncthreads();  // drains vmcnt -> staged data visible
    f16x8 af[4], bf[4];
#pragma unroll
    for (int i = 0; i < 4; ++i) {
      af[i] = *(const f16x8*)&smem[abase + i * 512];
      bf[i] = *(const f16x8*)&smem[bbase + i * 512];
    }
#pragma unroll
    for (int i = 0; i < 4; ++i)
#pragma unroll
      for (int j = 0; j < 4; ++j)
        acc[i][j] = __builtin_amdgcn_mfma_f32_16x16x32_f16(af[i], bf[j], acc[i][j], 0, 0, 0);
    __syncthreads();  // LDS reuse guard
  }

  // epilogue: D elem (row=(l>>4)*4+r, col=l&15) per 16x16 fragment [m89-verified]
#pragma unroll
  for (int i = 0; i < 4; ++i) {
    int row0 = bm + wr * 64 + i * 16 + (l >> 4) * 4;
#pragma unroll
    for (int r = 0; r < 4; ++r) {
      size_t rowoff = (size_t)(row0 + r) * N;
#pragma unroll
      for (int j = 0; j < 4; ++j) {
        int col = bn + wc * 64 + j * 16 + fr;
        if (col < N) {
          float v = acc[i][j][r] + bias[col];
          if (MODE == 1) v = res[rowoff + col] + gamma[col] * v;
          else if (MODE == 2) v = res[rowoff + col] + v;
          if (OUTF16) ((half_t*)outv)[rowoff + col] = (half_t)v;
          else ((float*)outv)[rowoff + col] = v;
        }
      }
    }
  }
}

// -------------------- softmax over last LP entries, one thread per (b,q,m) ------------------
__global__ void softmax_lp(float* __restrict__ a, int total, int LP) {
  int i = blockIdx.x * blockDim.x + threadIdx.x;
  if (i >= total) return;
  float* p = a + (size_t)i * LP;
  float mx = -1e30f;
  for (int j = 0; j < LP; ++j) mx = fmaxf(mx, p[j]);
  float s = 0.0f;
  for (int j = 0; j < LP; ++j) {
    float e = expf(p[j] - mx);
    p[j] = e;
    s += e;
  }
  float inv = 1.0f / s;
  for (int j = 0; j < LP; ++j) p[j] *= inv;
}

// -------------------- Injector sampling v2: 16 threads per (b,q,m), f16x8 gathers -----------
// v: (B,5376,768) fp16; offs: gp-ordered (gp=(b*1024+q)*6+m) x24; aw: gp x12; out: (B,1024,768)
__global__ __launch_bounds__(256) void sample_inj2(const half_t* __restrict__ v,
                                                   const float* __restrict__ offs,
                                                   const float* __restrict__ aw,
                                                   half_t* __restrict__ out) {
  int tid = threadIdx.x;
  int gp = blockIdx.x * 16 + (tid >> 4);
  int lane16 = tid & 15;
  int m = gp % MH;
  int bq = gp / MH;  // b*1024+q
  int q = bq & 1023;
  int b = bq >> 10;
  float refx = ((q & 31) + 0.5f) * (1.0f / 32.0f);
  float refy = ((q >> 5) + 0.5f) * (1.0f / 32.0f);
  const float* op = offs + (size_t)gp * 24;
  const float* ap = aw + (size_t)gp * 12;
  const half_t* vb = v + (size_t)b * 5376 * CD + m * DH + lane16 * 8;
  const int Hs[3] = {64, 32, 16};
  const int Ss[3] = {0, 4096, 5120};
  float accf[8];
#pragma unroll
  for (int i = 0; i < 8; ++i) accf[i] = 0.f;
#pragma unroll
  for (int lvl = 0; lvl < 3; ++lvl) {
    int H = Hs[lvl];
    float fH = (float)H;
    const half_t* vl = vb + (size_t)Ss[lvl] * CD;
#pragma unroll
    for (int p = 0; p < 4; ++p) {
      float xx = refx * fH + op[(lvl * 4 + p) * 2 + 0] - 0.5f;
      float yy = refy * fH + op[(lvl * 4 + p) * 2 + 1] - 0.5f;
      float x0f = floorf(xx), y0f = floorf(yy);
      float wx = xx - x0f, wy = yy - y0f;
      int x0 = (int)x0f, y0 = (int)y0f;
      float a = ap[lvl * 4 + p];
      f16x8 acch = (f16x8)(half_t)0.0f;
#pragma unroll
      for (int cy = 0; cy < 2; ++cy)
#pragma unroll
        for (int cx = 0; cx < 2; ++cx) {
          int xi = x0 + cx, yi = y0 + cy;
          bool valid = (xi >= 0) & (xi < H) & (yi >= 0) & (yi < H);
          float wgt = (cx ? wx : 1.f - wx) * (cy ? wy : 1.f - wy) * a;
          int xs = min(max(xi, 0), H - 1), ys = min(max(yi, 0), H - 1);
          half_t wch = (half_t)(valid ? wgt : 0.f);
          f16x8 vv = *(const f16x8*)(vl + (size_t)(ys * H + xs) * CD);
          acch += vv * wch;
        }
#pragma unroll
      for (int i = 0; i < 8; ++i) accf[i] += (float)acch[i];
    }
  }
  f16x8 r;
#pragma unroll
  for (int i = 0; i < 8; ++i) r[i] = (half_t)accf[i];
  *(f16x8*)(out + (size_t)bq * CD + m * DH + lane16 * 8) = r;
}

// -------------------- Extractor sampling v2: 16 threads per (b,q,m) -------------------------
// v: (B,1024,768) fp16; offs: gp-ordered (gp=(b*5376+q)*6+m) x8; aw: gp x4; out: (B,5376,768)
__global__ __launch_bounds__(256) void sample_ext2(const half_t* __restrict__ v,
                                                   const float* __restrict__ offs,
                                                   const float* __restrict__ aw,
                                                   half_t* __restrict__ out) {
  int tid = threadIdx.x;
  int gp = blockIdx.x * 16 + (tid >> 4);
  int lane16 = tid & 15;
  int m = gp % MH;
  int bq = gp / MH;  // b*5376+q
  int q = bq % 5376;
  int b = bq / 5376;
  float refx, refy;
  if (q < 4096) {
    refx = ((q & 63) + 0.5f) * (1.0f / 64.0f);
    refy = ((q >> 6) + 0.5f) * (1.0f / 64.0f);
  } else if (q < 5120) {
    int li = q - 4096;
    refx = ((li & 31) + 0.5f) * (1.0f / 32.0f);
    refy = ((li >> 5) + 0.5f) * (1.0f / 32.0f);
  } else {
    int li = q - 5120;
    refx = ((li & 15) + 0.5f) * (1.0f / 16.0f);
    refy = ((li >> 4) + 0.5f) * (1.0f / 16.0f);
  }
  const float* op = offs + (size_t)gp * 8;
  const float* ap = aw + (size_t)gp * 4;
  const half_t* vb = v + (size_t)b * 1024 * CD + m * DH + lane16 * 8;
  float accf[8];
#pragma unroll
  for (int i = 0; i < 8; ++i) accf[i] = 0.f;
#pragma unroll
  for (int p = 0; p < 4; ++p) {
    float xx = refx * 32.0f + op[p * 2 + 0] - 0.5f;
    float yy = refy * 32.0f + op[p * 2 + 1] - 0.5f;
    float x0f = floorf(xx), y0f = floorf(yy);
    float wx = xx - x0f, wy = yy - y0f;
    int x0 = (int)x0f, y0 = (int)y0f;
    float a = ap[p];
    f16x8 acch = (f16x8)(half_t)0.0f;
#pragma unroll
    for (int cy = 0; cy < 2; ++cy)
#pragma unroll
      for (int cx = 0; cx < 2; ++cx) {
        int xi = x0 + cx, yi = y0 + cy;
        bool valid = (xi >= 0) & (xi < 32) & (yi >= 0) & (yi < 32);
        float wgt = (cx ? wx : 1.f - wx) * (cy ? wy : 1.f - wy) * a;
        int xs = min(max(xi, 0), 31), ys = min(max(yi, 0), 31);
        half_t wch = (half_t)(valid ? wgt : 0.f);
        f16x8 vv = *(const f16x8*)(vb + (size_t)(ys * 32 + xs) * CD);
        acch += vv * wch;
      }
#pragma unroll
    for (int i = 0; i < 8; ++i) accf[i] += (float)acch[i];
  }
  f16x8 r;
#pragma unroll
  for (int i = 0; i < 8; ++i) r[i] = (half_t)accf[i];
  *(f16x8*)(out + (size_t)bq * CD + m * DH + lane16 * 8) = r;
}

// -------------------- depthwise 3x3 + bias + exact GELU (fp16 in/out) -----------------------
__global__ __launch_bounds__(192) void dwconv_gelu(const half_t* __restrict__ h,
                                                   const float* __restrict__ w,
                                                   const float* __restrict__ bias,
                                                   half_t* __restrict__ out) {
  int bt = blockIdx.x;
  int tok = bt % 5376;
  int b = bt / 5376;
  int c = threadIdx.x;
  int H, s, li;
  if (tok < 4096) { H = 64; s = 0; li = tok; }
  else if (tok < 5120) { H = 32; s = 4096; li = tok - 4096; }
  else { H = 16; s = 5120; li = tok - 5120; }
  int y = li / H, x = li % H;
  const half_t* hb = h + ((size_t)b * 5376 + s) * 192 + c;
  float acc = 0.0f;
#pragma unroll
  for (int dy = -1; dy <= 1; ++dy) {
    int yy = y + dy;
    if (yy < 0 || yy >= H) continue;
#pragma unroll
    for (int dx = -1; dx <= 1; ++dx) {
      int xx = x + dx;
      if (xx < 0 || xx >= H) continue;
      acc += w[c * 9 + (dy + 1) * 3 + (dx + 1)] * (float)hb[(size_t)(yy * H + xx) * 192];
    }
  }
  acc += bias[c];
  float g = 0.5f * acc * (1.0f + erff(acc * 0.70710678118654752f));
  out[((size_t)b * 5376 + tok) * 192 + c] = (half_t)g;
}

// -------------------- host launcher --------------------
extern "C" void kernel_launch(void* const* d_in, const int* in_sizes, int n_in,
                              void* d_out, int out_size, void* d_ws, size_t ws_size,
                              hipStream_t stream) {
  (void)in_sizes; (void)n_in; (void)out_size; (void)ws_size;
  const float* x        = (const float*)d_in[0];
  const float* c        = (const float*)d_in[1];
  const float* inj_n1g  = (const float*)d_in[2];
  const float* inj_n1b  = (const float*)d_in[3];
  const float* inj_n2g  = (const float*)d_in[4];
  const float* inj_n2b  = (const float*)d_in[5];
  const float* inj_off_w = (const float*)d_in[6];
  const float* inj_off_b = (const float*)d_in[7];
  const float* inj_aw_w = (const float*)d_in[8];
  const float* inj_aw_b = (const float*)d_in[9];
  const float* inj_val_w = (const float*)d_in[10];
  const float* inj_val_b = (const float*)d_in[11];
  const float* inj_out_w = (const float*)d_in[12];
  const float* inj_out_b = (const float*)d_in[13];
  const float* ext_n1g  = (const float*)d_in[14];
  const float* ext_n1b  = (const float*)d_in[15];
  const float* ext_n2g  = (const float*)d_in[16];
  const float* ext_n2b  = (const float*)d_in[17];
  const float* ext_off_w = (const float*)d_in[18];
  const float* ext_off_b = (const float*)d_in[19];
  const float* ext_aw_w = (const float*)d_in[20];
  const float* ext_aw_b = (const float*)d_in[21];
  const float* ext_val_w = (const float*)d_in[22];
  const float* ext_val_b = (const float*)d_in[23];
  const float* ext_out_w = (const float*)d_in[24];
  const float* ext_out_b = (const float*)d_in[25];
  const float* inj_gamma = (const float*)d_in[26];
  const float* ext_ng   = (const float*)d_in[27];
  const float* ext_nb   = (const float*)d_in[28];
  const float* ext_fc1_w = (const float*)d_in[29];
  const float* ext_fc1_b = (const float*)d_in[30];
  const float* ext_dw_w = (const float*)d_in[31];
  const float* ext_dw_b = (const float*)d_in[32];
  const float* ext_fc2_w = (const float*)d_in[33];
  const float* ext_fc2_b = (const float*)d_in[34];

  const int Sx = 4096;   // B*1024
  const int Sc = 21504;  // B*5376
  float* xout = (float*)d_out;
  float* cout = (float*)d_out + (size_t)Sx * CD;

  // ---- workspace layout (~141 MB) ----
  half_t* bigA   = (half_t*)d_ws;           // 16,515,072 h  LN_inj(c) / LN(cout)
  half_t* bigA2  = bigA + 16515072;         // 16,515,072 h  LN_ext(c)
  half_t* bigV   = bigA2 + 16515072;        // 16,515,072 h  v_inj / attn_ext
  half_t* smallA = bigV + 16515072;         //  3,145,728 h  LN(x)/LN(xout)
  half_t* smallB = smallA + 3145728;        //  3,145,728 h  attn_inj / v_ext
  half_t* h16    = smallB + 3145728;        //  4,128,768 h  fc1 out
  half_t* h2     = h16 + 4128768;           //  4,128,768 h  dwconv out
  half_t* w_inj_val = h2 + 4128768;         // 589,824
  half_t* w_inj_out = w_inj_val + 589824;   // 589,824
  half_t* w_ext_val = w_inj_out + 589824;   // 589,824
  half_t* w_ext_out = w_ext_val + 589824;   // 589,824
  half_t* w_fc2     = w_ext_out + 589824;   // 147,456 (768 x 192)
  half_t* w_inj_off = w_fc2 + 147456;       // 196,608 (256 x 768)
  half_t* w_inj_aw  = w_inj_off + 196608;   //  98,304 (128 x 768)
  half_t* w_ext_off = w_inj_aw + 98304;     //  98,304
  half_t* w_ext_aw  = w_ext_off + 98304;    //  98,304
  half_t* w_fc1     = w_ext_aw + 98304;     // 196,608 (256 x 768)
  float* offsb = (float*)(((uintptr_t)(w_fc1 + 196608) + 255) & ~(uintptr_t)255);
  float* awb = offsb + 1032192;

  // ---- fused weight conversion (10 segments, one launch) ----
  ConvArgs ca;
  const float* srcs[10] = {inj_val_w, inj_off_w, inj_aw_w, inj_out_w, ext_val_w,
                           ext_off_w, ext_aw_w, ext_out_w, ext_fc1_w, ext_fc2_w};
  half_t* dsts[10] = {w_inj_val, w_inj_off, w_inj_aw, w_inj_out, w_ext_val,
                      w_ext_off, w_ext_aw, w_ext_out, w_fc1, w_fc2};
  int Ks[10]    = {768, 768, 768, 768, 768, 768, 768, 768, 768, 192};
  int Ns[10]    = {768, 144, 72, 768, 768, 48, 24, 768, 192, 768};
  int Npads[10] = {768, 256, 128, 768, 768, 128, 128, 768, 256, 768};
  int base = 0;
  for (int i = 0; i < 10; ++i) {
    ca.W[i] = srcs[i]; ca.Wt[i] = dsts[i]; ca.K[i] = Ks[i]; ca.N[i] = Ns[i];
    ca.base[i] = base; base += Npads[i] * Ks[i];
  }
  ca.base[10] = base;
  convert_all<<<(base + 255) / 256, 256, 0, stream>>>(ca);

  // ---------------- Phase 1: Injector ----------------
  ln_f16<<<Sx, 256, 0, stream>>>(x, inj_n1g, inj_n1b, smallA);
  ln_dual<<<Sc, 256, 0, stream>>>(c, inj_n2g, inj_n2b, bigA, ext_n1g, ext_n1b, bigA2);
  gemm_mfma<0, 1><<<dim3(6, 168), 256, 0, stream>>>(bigA, w_inj_val, inj_val_b, nullptr, nullptr, bigV, Sc, 768, 768);
  gemm_mfma<0, 0><<<dim3(2, 32), 256, 0, stream>>>(smallA, w_inj_off, inj_off_b, nullptr, nullptr, offsb, Sx, 144, 768);
  gemm_mfma<0, 0><<<dim3(1, 32), 256, 0, stream>>>(smallA, w_inj_aw, inj_aw_b, nullptr, nullptr, awb, Sx, 72, 768);
  softmax_lp<<<(Sx * MH + 255) / 256, 256, 0, stream>>>(awb, Sx * MH, 12);
  sample_inj2<<<(Sx * MH) / 16, 256, 0, stream>>>(bigV, offsb, awb, smallB);
  gemm_mfma<1, 0><<<dim3(6, 32), 256, 0, stream>>>(smallB, w_inj_out, inj_out_b, x, inj_gamma, xout, Sx, 768, 768);

  // ---------------- Phase 2: Extractor ----------------
  ln_f16<<<Sx, 256, 0, stream>>>(xout, ext_n2g, ext_n2b, smallA);
  gemm_mfma<0, 1><<<dim3(6, 32), 256, 0, stream>>>(smallA, w_ext_val, ext_val_b, nullptr, nullptr, smallB, Sx, 768, 768);
  gemm_mfma<0, 0><<<dim3(1, 168), 256, 0, stream>>>(bigA2, w_ext_off, ext_off_b, nullptr, nullptr, offsb, Sc, 48, 768);
  gemm_mfma<0, 0><<<dim3(1, 168), 256, 0, stream>>>(bigA2, w_ext_aw, ext_aw_b, nullptr, nullptr, awb, Sc, 24, 768);
  softmax_lp<<<(Sc * MH + 255) / 256, 256, 0, stream>>>(awb, Sc * MH, 4);
  sample_ext2<<<(Sc * MH) / 16, 256, 0, stream>>>(smallB, offsb, awb, bigV);
  gemm_mfma<2, 0><<<dim3(6, 168), 256, 0, stream>>>(bigV, w_ext_out, ext_out_b, c, nullptr, cout, Sc, 768, 768);

  // ---------------- Phase 3: ConvFFN ----------------
  ln_f16<<<Sc, 256, 0, stream>>>(cout, ext_ng, ext_nb, bigA);
  gemm_mfma<0, 1><<<dim3(2, 168), 256, 0, stream>>>(bigA, w_fc1, ext_fc1_b, nullptr, nullptr, h16, Sc, 192, 768);
  dwconv_gelu<<<Sc, 192, 0, stream>>>(h16, ext_dw_w, ext_dw_b, h2);
  gemm_mfma<2, 0><<<dim3(6, 168), 256, 0, stream>>>(h2, w_fc2, ext_fc2_b, cout, nullptr, cout, Sc, 768, 192);
}

// Round 6
// 753.960 us; speedup vs baseline: 2.6509x; 1.0346x over previous
//
#include <hip/hip_runtime.h>
#include <math.h>
#include <stdint.h>

#define CD 768
#define DH 128
#define MH 6

using half_t = _Float16;
typedef __attribute__((ext_vector_type(8))) _Float16 f16x8;
typedef __attribute__((ext_vector_type(4))) float f32x4;

// -------------------- async global->LDS (16B per lane, wave-uniform LDS base) ---------------
__device__ __forceinline__ void gload16(const half_t* g, half_t* l) {
  __builtin_amdgcn_global_load_lds((__attribute__((address_space(1))) void*)g,
                                   (__attribute__((address_space(3))) void*)l, 16, 0, 0);
}

// -------------------- wave reduction --------------------
static __device__ __forceinline__ float wred(float v) {
#pragma unroll
  for (int off = 32; off > 0; off >>= 1) v += __shfl_down(v, off, 64);
  return v;
}

// -------------------- LayerNorm (fp32 in, fp16 out): one block per row of 768 ---------------
__global__ __launch_bounds__(256) void ln_f16(const float* __restrict__ in,
                                              const float* __restrict__ g,
                                              const float* __restrict__ b,
                                              half_t* __restrict__ out) {
  int row = blockIdx.x;
  const float* xp = in + (size_t)row * CD;
  half_t* op = out + (size_t)row * CD;
  int t = threadIdx.x;
  float v0 = xp[t], v1 = xp[t + 256], v2 = xp[t + 512];
  __shared__ float wsum[4];
  __shared__ float stat[2];
  int wid = t >> 6, lane = t & 63;
  float s = wred(v0 + v1 + v2);
  if (lane == 0) wsum[wid] = s;
  __syncthreads();
  if (t == 0) stat[0] = (wsum[0] + wsum[1] + wsum[2] + wsum[3]) * (1.0f / 768.0f);
  __syncthreads();
  float mu = stat[0];
  float d0 = v0 - mu, d1 = v1 - mu, d2 = v2 - mu;
  float q = wred(d0 * d0 + d1 * d1 + d2 * d2);
  if (lane == 0) wsum[wid] = q;
  __syncthreads();
  if (t == 0) {
    float var = (wsum[0] + wsum[1] + wsum[2] + wsum[3]) * (1.0f / 768.0f);
    stat[1] = 1.0f / sqrtf(var + 1e-6f);
  }
  __syncthreads();
  float rstd = stat[1];
  op[t]       = (half_t)(d0 * rstd * g[t]       + b[t]);
  op[t + 256] = (half_t)(d1 * rstd * g[t + 256] + b[t + 256]);
  op[t + 512] = (half_t)(d2 * rstd * g[t + 512] + b[t + 512]);
}

// -------------------- dual LayerNorm: same input row, two (g,b) pairs, two outputs ----------
__global__ __launch_bounds__(256) void ln_dual(const float* __restrict__ in,
                                               const float* __restrict__ g1,
                                               const float* __restrict__ b1,
                                               half_t* __restrict__ o1,
                                               const float* __restrict__ g2,
                                               const float* __restrict__ b2,
                                               half_t* __restrict__ o2) {
  int row = blockIdx.x;
  const float* xp = in + (size_t)row * CD;
  int t = threadIdx.x;
  float v0 = xp[t], v1 = xp[t + 256], v2 = xp[t + 512];
  __shared__ float wsum[4];
  __shared__ float stat[2];
  int wid = t >> 6, lane = t & 63;
  float s = wred(v0 + v1 + v2);
  if (lane == 0) wsum[wid] = s;
  __syncthreads();
  if (t == 0) stat[0] = (wsum[0] + wsum[1] + wsum[2] + wsum[3]) * (1.0f / 768.0f);
  __syncthreads();
  float mu = stat[0];
  float d0 = v0 - mu, d1 = v1 - mu, d2 = v2 - mu;
  float q = wred(d0 * d0 + d1 * d1 + d2 * d2);
  if (lane == 0) wsum[wid] = q;
  __syncthreads();
  if (t == 0) {
    float var = (wsum[0] + wsum[1] + wsum[2] + wsum[3]) * (1.0f / 768.0f);
    stat[1] = 1.0f / sqrtf(var + 1e-6f);
  }
  __syncthreads();
  float rstd = stat[1];
  half_t* p1 = o1 + (size_t)row * CD;
  half_t* p2 = o2 + (size_t)row * CD;
  float n0 = d0 * rstd, n1 = d1 * rstd, n2 = d2 * rstd;
  p1[t]       = (half_t)(n0 * g1[t]       + b1[t]);
  p1[t + 256] = (half_t)(n1 * g1[t + 256] + b1[t + 256]);
  p1[t + 512] = (half_t)(n2 * g1[t + 512] + b1[t + 512]);
  p2[t]       = (half_t)(n0 * g2[t]       + b2[t]);
  p2[t + 256] = (half_t)(n1 * g2[t + 256] + b2[t + 256]);
  p2[t + 512] = (half_t)(n2 * g2[t + 512] + b2[t + 512]);
}

// -------------------- fused weight convert: 10 segments, fp32 (K,N) -> fp16 (Npad,K) --------
struct ConvArgs {
  const float* W[10];
  half_t* Wt[10];
  int K[10];
  int N[10];
  int base[11];
};
__global__ __launch_bounds__(256) void convert_all(ConvArgs a) {
  int idx = blockIdx.x * 256 + threadIdx.x;
  if (idx >= a.base[10]) return;
  int s = 0;
  while (idx >= a.base[s + 1]) ++s;
  int local = idx - a.base[s];
  int K = a.K[s], N = a.N[s];
  int n = local / K, k = local - n * K;
  a.Wt[s][local] = (n < N) ? (half_t)a.W[s][(size_t)k * N + n] : (half_t)0.0f;
}

// -------------------- MFMA fp16 GEMM, 2-phase double-buffered + XCD swizzle -----------------
// A: (M,K) fp16 row-major. Wt: (Npad,K) fp16 row-major (= W^T, zero-padded cols).
// out row stride = N. MODE 0: acc+bias; 1: res + gamma*(acc+bias); 2: res + acc+bias.
// M%128==0, K%32==0, grid = (Npad/128, M/128), 256 threads.
template <int MODE, int OUTF16>
__global__ __launch_bounds__(256) void gemm_mfma(const half_t* __restrict__ A,
                                                 const half_t* __restrict__ Wt,
                                                 const float* __restrict__ bias,
                                                 const float* __restrict__ res,
                                                 const float* __restrict__ gamma,
                                                 void* __restrict__ outv,
                                                 int M, int N, int K) {
  __shared__ half_t smem[16384];  // 2 bufs x (As [128][32] + Bs [128][32])
  const int tid = threadIdx.x;
  const int w = tid >> 6;
  const int l = tid & 63;
  const int wr = w >> 1, wc = w & 1;

  // XCD-bijective block swizzle (m204): contiguous tile chunks per XCD
  const int nwg = gridDim.x * gridDim.y;
  const int orig = blockIdx.x + blockIdx.y * gridDim.x;
  const int qq = nwg >> 3, rr = nwg & 7;
  const int xcd = orig & 7, idx8 = orig >> 3;
  const int sw = ((xcd < rr) ? xcd * (qq + 1) : rr * (qq + 1) + (xcd - rr) * qq) + idx8;
  const int bm = (sw / gridDim.x) * 128;
  const int bn = (sw % gridDim.x) * 128;

  f32x4 acc[4][4];
#pragma unroll
  for (int i = 0; i < 4; ++i)
#pragma unroll
    for (int j = 0; j < 4; ++j) acc[i][j] = (f32x4){0.f, 0.f, 0.f, 0.f};

  // staging: wave w fills rows [j0*16, j0*16+32); lane covers row j*16+(l>>2), col (l&3)*8
  const int j0 = w * 2;
  const int sr = l >> 2;
  const int sc = (l & 3) * 8;
  const half_t* Ag0 = A + (size_t)(bm + j0 * 16 + sr) * K + sc;
  const half_t* Ag1 = Ag0 + (size_t)16 * K;
  const half_t* Bg0 = Wt + (size_t)(bn + j0 * 16 + sr) * K + sc;
  const half_t* Bg1 = Bg0 + (size_t)16 * K;

  const int fr = l & 15;
  const int fk = (l >> 4) * 8;
  const int abase = (wr * 64 + fr) * 32 + fk;
  const int bbase = 4096 + (wc * 64 + fr) * 32 + fk;

  auto STAGE = [&](int buf, int k0) {
    half_t* base = smem + buf * 8192;
    gload16(Ag0 + k0, base + j0 * 512);
    gload16(Ag1 + k0, base + j0 * 512 + 512);
    gload16(Bg0 + k0, base + 4096 + j0 * 512);
    gload16(Bg1 + k0, base + 4096 + j0 * 512 + 512);
  };

  const int NT = K >> 5;
  STAGE(0, 0);
  __syncthreads();  // buf0 staged
  int cur = 0;
  for (int t = 0; t < NT; ++t) {
    if (t + 1 < NT) STAGE(cur ^ 1, (t + 1) << 5);  // issue next tile EARLY (overlaps compute)
    const half_t* rb = smem + cur * 8192;
    f16x8 af[4], bf[4];
#pragma unroll
    for (int i = 0; i < 4; ++i) {
      af[i] = *(const f16x8*)&rb[abase + i * 512];
      bf[i] = *(const f16x8*)&rb[bbase + i * 512];
    }
#pragma unroll
    for (int i = 0; i < 4; ++i)
#pragma unroll
      for (int j = 0; j < 4; ++j)
        acc[i][j] = __builtin_amdgcn_mfma_f32_16x16x32_f16(af[i], bf[j], acc[i][j], 0, 0, 0);
    __syncthreads();  // drains vmcnt (next tile staged) + guards LDS reuse
    cur ^= 1;
  }

  // epilogue: D elem (row=(l>>4)*4+r, col=l&15) per 16x16 fragment [m89-verified]
#pragma unroll
  for (int i = 0; i < 4; ++i) {
    int row0 = bm + wr * 64 + i * 16 + (l >> 4) * 4;
#pragma unroll
    for (int r = 0; r < 4; ++r) {
      size_t rowoff = (size_t)(row0 + r) * N;
#pragma unroll
      for (int j = 0; j < 4; ++j) {
        int col = bn + wc * 64 + j * 16 + fr;
        if (col < N) {
          float v = acc[i][j][r] + bias[col];
          if (MODE == 1) v = res[rowoff + col] + gamma[col] * v;
          else if (MODE == 2) v = res[rowoff + col] + v;
          if (OUTF16) ((half_t*)outv)[rowoff + col] = (half_t)v;
          else ((float*)outv)[rowoff + col] = v;
        }
      }
    }
  }
}

// -------------------- softmax over last LP entries, one thread per (b,q,m) ------------------
__global__ void softmax_lp(float* __restrict__ a, int total, int LP) {
  int i = blockIdx.x * blockDim.x + threadIdx.x;
  if (i >= total) return;
  float* p = a + (size_t)i * LP;
  float mx = -1e30f;
  for (int j = 0; j < LP; ++j) mx = fmaxf(mx, p[j]);
  float s = 0.0f;
  for (int j = 0; j < LP; ++j) {
    float e = expf(p[j] - mx);
    p[j] = e;
    s += e;
  }
  float inv = 1.0f / s;
  for (int j = 0; j < LP; ++j) p[j] *= inv;
}

// -------------------- Injector sampling v2: 16 threads per (b,q,m), f16x8 gathers -----------
__global__ __launch_bounds__(256) void sample_inj2(const half_t* __restrict__ v,
                                                   const float* __restrict__ offs,
                                                   const float* __restrict__ aw,
                                                   half_t* __restrict__ out) {
  int tid = threadIdx.x;
  int gp = blockIdx.x * 16 + (tid >> 4);
  int lane16 = tid & 15;
  int m = gp % MH;
  int bq = gp / MH;  // b*1024+q
  int q = bq & 1023;
  int b = bq >> 10;
  float refx = ((q & 31) + 0.5f) * (1.0f / 32.0f);
  float refy = ((q >> 5) + 0.5f) * (1.0f / 32.0f);
  const float* op = offs + (size_t)gp * 24;
  const float* ap = aw + (size_t)gp * 12;
  const half_t* vb = v + (size_t)b * 5376 * CD + m * DH + lane16 * 8;
  const int Hs[3] = {64, 32, 16};
  const int Ss[3] = {0, 4096, 5120};
  float accf[8];
#pragma unroll
  for (int i = 0; i < 8; ++i) accf[i] = 0.f;
#pragma unroll
  for (int lvl = 0; lvl < 3; ++lvl) {
    int H = Hs[lvl];
    float fH = (float)H;
    const half_t* vl = vb + (size_t)Ss[lvl] * CD;
#pragma unroll
    for (int p = 0; p < 4; ++p) {
      float xx = refx * fH + op[(lvl * 4 + p) * 2 + 0] - 0.5f;
      float yy = refy * fH + op[(lvl * 4 + p) * 2 + 1] - 0.5f;
      float x0f = floorf(xx), y0f = floorf(yy);
      float wx = xx - x0f, wy = yy - y0f;
      int x0 = (int)x0f, y0 = (int)y0f;
      float a = ap[lvl * 4 + p];
      f16x8 acch = (f16x8)(half_t)0.0f;
#pragma unroll
      for (int cy = 0; cy < 2; ++cy)
#pragma unroll
        for (int cx = 0; cx < 2; ++cx) {
          int xi = x0 + cx, yi = y0 + cy;
          bool valid = (xi >= 0) & (xi < H) & (yi >= 0) & (yi < H);
          float wgt = (cx ? wx : 1.f - wx) * (cy ? wy : 1.f - wy) * a;
          int xs = min(max(xi, 0), H - 1), ys = min(max(yi, 0), H - 1);
          half_t wch = (half_t)(valid ? wgt : 0.f);
          f16x8 vv = *(const f16x8*)(vl + (size_t)(ys * H + xs) * CD);
          acch += vv * wch;
        }
#pragma unroll
      for (int i = 0; i < 8; ++i) accf[i] += (float)acch[i];
    }
  }
  f16x8 r;
#pragma unroll
  for (int i = 0; i < 8; ++i) r[i] = (half_t)accf[i];
  *(f16x8*)(out + (size_t)bq * CD + m * DH + lane16 * 8) = r;
}

// -------------------- Extractor sampling v2: 16 threads per (b,q,m) -------------------------
__global__ __launch_bounds__(256) void sample_ext2(const half_t* __restrict__ v,
                                                   const float* __restrict__ offs,
                                                   const float* __restrict__ aw,
                                                   half_t* __restrict__ out) {
  int tid = threadIdx.x;
  int gp = blockIdx.x * 16 + (tid >> 4);
  int lane16 = tid & 15;
  int m = gp % MH;
  int bq = gp / MH;  // b*5376+q
  int q = bq % 5376;
  int b = bq / 5376;
  float refx, refy;
  if (q < 4096) {
    refx = ((q & 63) + 0.5f) * (1.0f / 64.0f);
    refy = ((q >> 6) + 0.5f) * (1.0f / 64.0f);
  } else if (q < 5120) {
    int li = q - 4096;
    refx = ((li & 31) + 0.5f) * (1.0f / 32.0f);
    refy = ((li >> 5) + 0.5f) * (1.0f / 32.0f);
  } else {
    int li = q - 5120;
    refx = ((li & 15) + 0.5f) * (1.0f / 16.0f);
    refy = ((li >> 4) + 0.5f) * (1.0f / 16.0f);
  }
  const float* op = offs + (size_t)gp * 8;
  const float* ap = aw + (size_t)gp * 4;
  const half_t* vb = v + (size_t)b * 1024 * CD + m * DH + lane16 * 8;
  float accf[8];
#pragma unroll
  for (int i = 0; i < 8; ++i) accf[i] = 0.f;
#pragma unroll
  for (int p = 0; p < 4; ++p) {
    float xx = refx * 32.0f + op[p * 2 + 0] - 0.5f;
    float yy = refy * 32.0f + op[p * 2 + 1] - 0.5f;
    float x0f = floorf(xx), y0f = floorf(yy);
    float wx = xx - x0f, wy = yy - y0f;
    int x0 = (int)x0f, y0 = (int)y0f;
    float a = ap[p];
    f16x8 acch = (f16x8)(half_t)0.0f;
#pragma unroll
    for (int cy = 0; cy < 2; ++cy)
#pragma unroll
      for (int cx = 0; cx < 2; ++cx) {
        int xi = x0 + cx, yi = y0 + cy;
        bool valid = (xi >= 0) & (xi < 32) & (yi >= 0) & (yi < 32);
        float wgt = (cx ? wx : 1.f - wx) * (cy ? wy : 1.f - wy) * a;
        int xs = min(max(xi, 0), 31), ys = min(max(yi, 0), 31);
        half_t wch = (half_t)(valid ? wgt : 0.f);
        f16x8 vv = *(const f16x8*)(vb + (size_t)(ys * 32 + xs) * CD);
        acch += vv * wch;
      }
#pragma unroll
    for (int i = 0; i < 8; ++i) accf[i] += (float)acch[i];
  }
  f16x8 r;
#pragma unroll
  for (int i = 0; i < 8; ++i) r[i] = (half_t)accf[i];
  *(f16x8*)(out + (size_t)bq * CD + m * DH + lane16 * 8) = r;
}

// -------------------- depthwise 3x3 + bias + exact GELU, 8 channels/thread ------------------
// h: (B,5376,192) fp16; grid covers Sc*24 groups of 8 channels
__global__ __launch_bounds__(256) void dwconv_gelu(const half_t* __restrict__ h,
                                                   const float* __restrict__ w,
                                                   const float* __restrict__ bias,
                                                   half_t* __restrict__ out) {
  int g = blockIdx.x * 256 + threadIdx.x;
  int cg = g % 24;
  int tl = g / 24;          // b*5376 + tok
  int tok = tl % 5376;
  int b = tl / 5376;
  int H, s, li;
  if (tok < 4096) { H = 64; s = 0; li = tok; }
  else if (tok < 5120) { H = 32; s = 4096; li = tok - 4096; }
  else { H = 16; s = 5120; li = tok - 5120; }
  int y = li / H, x = li % H;
  int c0 = cg * 8;
  const half_t* hb = h + ((size_t)b * 5376 + s) * 192 + c0;
  float acc[8];
#pragma unroll
  for (int i = 0; i < 8; ++i) acc[i] = bias[c0 + i];
#pragma unroll
  for (int dy = -1; dy <= 1; ++dy) {
    int yy = y + dy;
    if (yy < 0 || yy >= H) continue;
#pragma unroll
    for (int dx = -1; dx <= 1; ++dx) {
      int xx = x + dx;
      if (xx < 0 || xx >= H) continue;
      int k = (dy + 1) * 3 + (dx + 1);
      f16x8 vv = *(const f16x8*)(hb + (size_t)(yy * H + xx) * 192);
#pragma unroll
      for (int i = 0; i < 8; ++i) acc[i] += w[(c0 + i) * 9 + k] * (float)vv[i];
    }
  }
  f16x8 r;
#pragma unroll
  for (int i = 0; i < 8; ++i)
    r[i] = (half_t)(0.5f * acc[i] * (1.0f + erff(acc[i] * 0.70710678118654752f)));
  *(f16x8*)(out + (size_t)tl * 192 + c0) = r;
}

// -------------------- host launcher --------------------
extern "C" void kernel_launch(void* const* d_in, const int* in_sizes, int n_in,
                              void* d_out, int out_size, void* d_ws, size_t ws_size,
                              hipStream_t stream) {
  (void)in_sizes; (void)n_in; (void)out_size; (void)ws_size;
  const float* x        = (const float*)d_in[0];
  const float* c        = (const float*)d_in[1];
  const float* inj_n1g  = (const float*)d_in[2];
  const float* inj_n1b  = (const float*)d_in[3];
  const float* inj_n2g  = (const float*)d_in[4];
  const float* inj_n2b  = (const float*)d_in[5];
  const float* inj_off_w = (const float*)d_in[6];
  const float* inj_off_b = (const float*)d_in[7];
  const float* inj_aw_w = (const float*)d_in[8];
  const float* inj_aw_b = (const float*)d_in[9];
  const float* inj_val_w = (const float*)d_in[10];
  const float* inj_val_b = (const float*)d_in[11];
  const float* inj_out_w = (const float*)d_in[12];
  const float* inj_out_b = (const float*)d_in[13];
  const float* ext_n1g  = (const float*)d_in[14];
  const float* ext_n1b  = (const float*)d_in[15];
  const float* ext_n2g  = (const float*)d_in[16];
  const float* ext_n2b  = (const float*)d_in[17];
  const float* ext_off_w = (const float*)d_in[18];
  const float* ext_off_b = (const float*)d_in[19];
  const float* ext_aw_w = (const float*)d_in[20];
  const float* ext_aw_b = (const float*)d_in[21];
  const float* ext_val_w = (const float*)d_in[22];
  const float* ext_val_b = (const float*)d_in[23];
  const float* ext_out_w = (const float*)d_in[24];
  const float* ext_out_b = (const float*)d_in[25];
  const float* inj_gamma = (const float*)d_in[26];
  const float* ext_ng   = (const float*)d_in[27];
  const float* ext_nb   = (const float*)d_in[28];
  const float* ext_fc1_w = (const float*)d_in[29];
  const float* ext_fc1_b = (const float*)d_in[30];
  const float* ext_dw_w = (const float*)d_in[31];
  const float* ext_dw_b = (const float*)d_in[32];
  const float* ext_fc2_w = (const float*)d_in[33];
  const float* ext_fc2_b = (const float*)d_in[34];

  const int Sx = 4096;   // B*1024
  const int Sc = 21504;  // B*5376
  float* xout = (float*)d_out;
  float* cout = (float*)d_out + (size_t)Sx * CD;

  // ---- workspace layout (~141 MB) ----
  half_t* bigA   = (half_t*)d_ws;           // 16,515,072 h  LN_inj(c) / LN(cout)
  half_t* bigA2  = bigA + 16515072;         // 16,515,072 h  LN_ext(c)
  half_t* bigV   = bigA2 + 16515072;        // 16,515,072 h  v_inj / attn_ext
  half_t* smallA = bigV + 16515072;         //  3,145,728 h  LN(x)/LN(xout)
  half_t* smallB = smallA + 3145728;        //  3,145,728 h  attn_inj / v_ext
  half_t* h16    = smallB + 3145728;        //  4,128,768 h  fc1 out
  half_t* h2     = h16 + 4128768;           //  4,128,768 h  dwconv out
  half_t* w_inj_val = h2 + 4128768;         // 589,824
  half_t* w_inj_out = w_inj_val + 589824;   // 589,824
  half_t* w_ext_val = w_inj_out + 589824;   // 589,824
  half_t* w_ext_out = w_ext_val + 589824;   // 589,824
  half_t* w_fc2     = w_ext_out + 589824;   // 147,456 (768 x 192)
  half_t* w_inj_off = w_fc2 + 147456;       // 196,608 (256 x 768)
  half_t* w_inj_aw  = w_inj_off + 196608;   //  98,304 (128 x 768)
  half_t* w_ext_off = w_inj_aw + 98304;     //  98,304
  half_t* w_ext_aw  = w_ext_off + 98304;    //  98,304
  half_t* w_fc1     = w_ext_aw + 98304;     // 196,608 (256 x 768)
  float* offsb = (float*)(((uintptr_t)(w_fc1 + 196608) + 255) & ~(uintptr_t)255);
  float* awb = offsb + 1032192;

  // ---- fused weight conversion (10 segments, one launch) ----
  ConvArgs ca;
  const float* srcs[10] = {inj_val_w, inj_off_w, inj_aw_w, inj_out_w, ext_val_w,
                           ext_off_w, ext_aw_w, ext_out_w, ext_fc1_w, ext_fc2_w};
  half_t* dsts[10] = {w_inj_val, w_inj_off, w_inj_aw, w_inj_out, w_ext_val,
                      w_ext_off, w_ext_aw, w_ext_out, w_fc1, w_fc2};
  int Ks[10]    = {768, 768, 768, 768, 768, 768, 768, 768, 768, 192};
  int Ns[10]    = {768, 144, 72, 768, 768, 48, 24, 768, 192, 768};
  int Npads[10] = {768, 256, 128, 768, 768, 128, 128, 768, 256, 768};
  int base = 0;
  for (int i = 0; i < 10; ++i) {
    ca.W[i] = srcs[i]; ca.Wt[i] = dsts[i]; ca.K[i] = Ks[i]; ca.N[i] = Ns[i];
    ca.base[i] = base; base += Npads[i] * Ks[i];
  }
  ca.base[10] = base;
  convert_all<<<(base + 255) / 256, 256, 0, stream>>>(ca);

  // ---------------- Phase 1: Injector ----------------
  ln_f16<<<Sx, 256, 0, stream>>>(x, inj_n1g, inj_n1b, smallA);
  ln_dual<<<Sc, 256, 0, stream>>>(c, inj_n2g, inj_n2b, bigA, ext_n1g, ext_n1b, bigA2);
  gemm_mfma<0, 1><<<dim3(6, 168), 256, 0, stream>>>(bigA, w_inj_val, inj_val_b, nullptr, nullptr, bigV, Sc, 768, 768);
  gemm_mfma<0, 0><<<dim3(2, 32), 256, 0, stream>>>(smallA, w_inj_off, inj_off_b, nullptr, nullptr, offsb, Sx, 144, 768);
  gemm_mfma<0, 0><<<dim3(1, 32), 256, 0, stream>>>(smallA, w_inj_aw, inj_aw_b, nullptr, nullptr, awb, Sx, 72, 768);
  softmax_lp<<<(Sx * MH + 255) / 256, 256, 0, stream>>>(awb, Sx * MH, 12);
  sample_inj2<<<(Sx * MH) / 16, 256, 0, stream>>>(bigV, offsb, awb, smallB);
  gemm_mfma<1, 0><<<dim3(6, 32), 256, 0, stream>>>(smallB, w_inj_out, inj_out_b, x, inj_gamma, xout, Sx, 768, 768);

  // ---------------- Phase 2: Extractor ----------------
  ln_f16<<<Sx, 256, 0, stream>>>(xout, ext_n2g, ext_n2b, smallA);
  gemm_mfma<0, 1><<<dim3(6, 32), 256, 0, stream>>>(smallA, w_ext_val, ext_val_b, nullptr, nullptr, smallB, Sx, 768, 768);
  gemm_mfma<0, 0><<<dim3(1, 168), 256, 0, stream>>>(bigA2, w_ext_off, ext_off_b, nullptr, nullptr, offsb, Sc, 48, 768);
  gemm_mfma<0, 0><<<dim3(1, 168), 256, 0, stream>>>(bigA2, w_ext_aw, ext_aw_b, nullptr, nullptr, awb, Sc, 24, 768);
  softmax_lp<<<(Sc * MH + 255) / 256, 256, 0, stream>>>(awb, Sc * MH, 4);
  sample_ext2<<<(Sc * MH) / 16, 256, 0, stream>>>(smallB, offsb, awb, bigV);
  gemm_mfma<2, 0><<<dim3(6, 168), 256, 0, stream>>>(bigV, w_ext_out, ext_out_b, c, nullptr, cout, Sc, 768, 768);

  // ---------------- Phase 3: ConvFFN ----------------
  ln_f16<<<Sc, 256, 0, stream>>>(cout, ext_ng, ext_nb, bigA);
  gemm_mfma<0, 1><<<dim3(2, 168), 256, 0, stream>>>(bigA, w_fc1, ext_fc1_b, nullptr, nullptr, h16, Sc, 192, 768);
  dwconv_gelu<<<(Sc * 24) / 256, 256, 0, stream>>>(h16, ext_dw_w, ext_dw_b, h2);
  gemm_mfma<2, 0><<<dim3(6, 168), 256, 0, stream>>>(h2, w_fc2, ext_fc2_b, cout, nullptr, cout, Sc, 768, 192);
}

// Round 11
// 723.123 us; speedup vs baseline: 2.7640x; 1.0426x over previous
//
#include <hip/hip_runtime.h>
#include <math.h>
#include <stdint.h>

#define CD 768
#define DH 128
#define MH 6

using half_t = _Float16;
typedef __attribute__((ext_vector_type(8))) _Float16 f16x8;
typedef __attribute__((ext_vector_type(4))) float f32x4;

// -------------------- async global->LDS (16B per lane, wave-uniform LDS base) ---------------
__device__ __forceinline__ void gload16(const half_t* g, half_t* l) {
  __builtin_amdgcn_global_load_lds((__attribute__((address_space(1))) void*)g,
                                   (__attribute__((address_space(3))) void*)l, 16, 0, 0);
}

// -------------------- wave reduction --------------------
static __device__ __forceinline__ float wred(float v) {
#pragma unroll
  for (int off = 32; off > 0; off >>= 1) v += __shfl_down(v, off, 64);
  return v;
}

// -------------------- LayerNorm (fp32 in, fp16 out): one block per row of 768 ---------------
__global__ __launch_bounds__(256) void ln_f16(const float* __restrict__ in,
                                              const float* __restrict__ g,
                                              const float* __restrict__ b,
                                              half_t* __restrict__ out) {
  int row = blockIdx.x;
  const float* xp = in + (size_t)row * CD;
  half_t* op = out + (size_t)row * CD;
  int t = threadIdx.x;
  float v0 = xp[t], v1 = xp[t + 256], v2 = xp[t + 512];
  __shared__ float wsum[4];
  __shared__ float stat[2];
  int wid = t >> 6, lane = t & 63;
  float s = wred(v0 + v1 + v2);
  if (lane == 0) wsum[wid] = s;
  __syncthreads();
  if (t == 0) stat[0] = (wsum[0] + wsum[1] + wsum[2] + wsum[3]) * (1.0f / 768.0f);
  __syncthreads();
  float mu = stat[0];
  float d0 = v0 - mu, d1 = v1 - mu, d2 = v2 - mu;
  float q = wred(d0 * d0 + d1 * d1 + d2 * d2);
  if (lane == 0) wsum[wid] = q;
  __syncthreads();
  if (t == 0) {
    float var = (wsum[0] + wsum[1] + wsum[2] + wsum[3]) * (1.0f / 768.0f);
    stat[1] = 1.0f / sqrtf(var + 1e-6f);
  }
  __syncthreads();
  float rstd = stat[1];
  op[t]       = (half_t)(d0 * rstd * g[t]       + b[t]);
  op[t + 256] = (half_t)(d1 * rstd * g[t + 256] + b[t + 256]);
  op[t + 512] = (half_t)(d2 * rstd * g[t + 512] + b[t + 512]);
}

// -------------------- dual LayerNorm: same input row, two (g,b) pairs, two outputs ----------
__global__ __launch_bounds__(256) void ln_dual(const float* __restrict__ in,
                                               const float* __restrict__ g1,
                                               const float* __restrict__ b1,
                                               half_t* __restrict__ o1,
                                               const float* __restrict__ g2,
                                               const float* __restrict__ b2,
                                               half_t* __restrict__ o2) {
  int row = blockIdx.x;
  const float* xp = in + (size_t)row * CD;
  int t = threadIdx.x;
  float v0 = xp[t], v1 = xp[t + 256], v2 = xp[t + 512];
  __shared__ float wsum[4];
  __shared__ float stat[2];
  int wid = t >> 6, lane = t & 63;
  float s = wred(v0 + v1 + v2);
  if (lane == 0) wsum[wid] = s;
  __syncthreads();
  if (t == 0) stat[0] = (wsum[0] + wsum[1] + wsum[2] + wsum[3]) * (1.0f / 768.0f);
  __syncthreads();
  float mu = stat[0];
  float d0 = v0 - mu, d1 = v1 - mu, d2 = v2 - mu;
  float q = wred(d0 * d0 + d1 * d1 + d2 * d2);
  if (lane == 0) wsum[wid] = q;
  __syncthreads();
  if (t == 0) {
    float var = (wsum[0] + wsum[1] + wsum[2] + wsum[3]) * (1.0f / 768.0f);
    stat[1] = 1.0f / sqrtf(var + 1e-6f);
  }
  __syncthreads();
  float rstd = stat[1];
  half_t* p1 = o1 + (size_t)row * CD;
  half_t* p2 = o2 + (size_t)row * CD;
  float n0 = d0 * rstd, n1 = d1 * rstd, n2 = d2 * rstd;
  p1[t]       = (half_t)(n0 * g1[t]       + b1[t]);
  p1[t + 256] = (half_t)(n1 * g1[t + 256] + b1[t + 256]);
  p1[t + 512] = (half_t)(n2 * g1[t + 512] + b1[t + 512]);
  p2[t]       = (half_t)(n0 * g2[t]       + b2[t]);
  p2[t + 256] = (half_t)(n1 * g2[t + 256] + b2[t + 256]);
  p2[t + 512] = (half_t)(n2 * g2[t + 512] + b2[t + 512]);
}

// -------------------- fused weight convert: 10 segments, fp32 (K,N) -> fp16 (Npad,K) --------
struct ConvArgs {
  const float* W[10];
  half_t* Wt[10];
  int K[10];
  int N[10];
  int base[11];
};
__global__ __launch_bounds__(256) void convert_all(ConvArgs a) {
  int idx = blockIdx.x * 256 + threadIdx.x;
  if (idx >= a.base[10]) return;
  int s = 0;
  while (idx >= a.base[s + 1]) ++s;
  int local = idx - a.base[s];
  int K = a.K[s], N = a.N[s];
  int n = local / K, k = local - n * K;
  a.Wt[s][local] = (n < N) ? (half_t)a.W[s][(size_t)k * N + n] : (half_t)0.0f;
}

// -------------------- MFMA fp16 GEMM, counted-vmcnt double-buffer + XCD swizzle -------------
// A: (M,K) fp16 row-major. Wt: (Npad,K) fp16 row-major (= W^T, zero-padded cols).
// out row stride = N. MODE 0: acc+bias; 1: res + gamma*(acc+bias); 2: res + acc+bias.
// M%128==0, K%32==0 (K>=64), grid = (Npad/128, M/128), 256 threads.
template <int MODE, int OUTF16>
__global__ __launch_bounds__(256) void gemm_mfma(const half_t* __restrict__ A,
                                                 const half_t* __restrict__ Wt,
                                                 const float* __restrict__ bias,
                                                 const float* __restrict__ res,
                                                 const float* __restrict__ gamma,
                                                 void* __restrict__ outv,
                                                 int M, int N, int K) {
  __shared__ half_t smem[16384];  // 2 bufs x (As [128][32] + Bs [128][32])
  const int tid = threadIdx.x;
  const int w = tid >> 6;
  const int l = tid & 63;
  const int wr = w >> 1, wc = w & 1;

  // XCD-bijective block swizzle (m204): contiguous tile chunks per XCD
  const int nwg = gridDim.x * gridDim.y;
  const int orig = blockIdx.x + blockIdx.y * gridDim.x;
  const int qq = nwg >> 3, rr = nwg & 7;
  const int xcd = orig & 7, idx8 = orig >> 3;
  const int sw = ((xcd < rr) ? xcd * (qq + 1) : rr * (qq + 1) + (xcd - rr) * qq) + idx8;
  const int bm = (sw / gridDim.x) * 128;
  const int bn = (sw % gridDim.x) * 128;

  f32x4 acc[4][4];
#pragma unroll
  for (int i = 0; i < 4; ++i)
#pragma unroll
    for (int j = 0; j < 4; ++j) acc[i][j] = (f32x4){0.f, 0.f, 0.f, 0.f};

  // staging: wave w fills rows [j0*16, j0*16+32); lane covers row j*16+(l>>2), col (l&3)*8
  const int j0 = w * 2;
  const int sr = l >> 2;
  const int sc = (l & 3) * 8;
  const half_t* Ag0 = A + (size_t)(bm + j0 * 16 + sr) * K + sc;
  const half_t* Ag1 = Ag0 + (size_t)16 * K;
  const half_t* Bg0 = Wt + (size_t)(bn + j0 * 16 + sr) * K + sc;
  const half_t* Bg1 = Bg0 + (size_t)16 * K;

  const int fr = l & 15;
  const int fk = (l >> 4) * 8;
  const int abase = (wr * 64 + fr) * 32 + fk;
  const int bbase = 4096 + (wc * 64 + fr) * 32 + fk;

  auto STAGE = [&](int buf, int k0) {
    half_t* base = smem + buf * 8192;
    gload16(Ag0 + k0, base + j0 * 512);
    gload16(Ag1 + k0, base + j0 * 512 + 512);
    gload16(Bg0 + k0, base + 4096 + j0 * 512);
    gload16(Bg1 + k0, base + 4096 + j0 * 512 + 512);
  };

  const int NT = K >> 5;
  // depth-2 prologue: 8 loads/thread in flight
  STAGE(0, 0);
  if (NT > 1) STAGE(1, 32);

  for (int t = 0; t < NT; ++t) {
    const int cur = t & 1;
    // wait for tile t only; keep tile t+1 (4 loads) in flight [T4: counted vmcnt, never 0 in-loop]
    if (t < NT - 1) {
      asm volatile("s_waitcnt vmcnt(4)" ::: "memory");
    } else {
      asm volatile("s_waitcnt vmcnt(0)" ::: "memory");
    }
    asm volatile("s_barrier" ::: "memory");  // all waves' tile-t loads landed in LDS

    const half_t* rb = smem + cur * 8192;
    f16x8 af[4], bf[4];
#pragma unroll
    for (int i = 0; i < 4; ++i) {
      af[i] = *(const f16x8*)&rb[abase + i * 512];
      bf[i] = *(const f16x8*)&rb[bbase + i * 512];
    }
    asm volatile("s_waitcnt lgkmcnt(0)" ::: "memory");  // my ds_reads retired
    __builtin_amdgcn_sched_barrier(0);
    asm volatile("s_barrier" ::: "memory");  // ALL waves done reading buf[cur] -> safe to overwrite

    if (t + 2 < NT) STAGE(cur, (t + 2) << 5);  // issue tile t+2; lands >=2 iterations later

#pragma unroll
    for (int i = 0; i < 4; ++i)
#pragma unroll
      for (int j = 0; j < 4; ++j)
        acc[i][j] = __builtin_amdgcn_mfma_f32_16x16x32_f16(af[i], bf[j], acc[i][j], 0, 0, 0);
  }

  // epilogue: D elem (row=(l>>4)*4+r, col=l&15) per 16x16 fragment [m89-verified]
#pragma unroll
  for (int i = 0; i < 4; ++i) {
    int row0 = bm + wr * 64 + i * 16 + (l >> 4) * 4;
#pragma unroll
    for (int r = 0; r < 4; ++r) {
      size_t rowoff = (size_t)(row0 + r) * N;
#pragma unroll
      for (int j = 0; j < 4; ++j) {
        int col = bn + wc * 64 + j * 16 + fr;
        if (col < N) {
          float v = acc[i][j][r] + bias[col];
          if (MODE == 1) v = res[rowoff + col] + gamma[col] * v;
          else if (MODE == 2) v = res[rowoff + col] + v;
          if (OUTF16) ((half_t*)outv)[rowoff + col] = (half_t)v;
          else ((float*)outv)[rowoff + col] = v;
        }
      }
    }
  }
}

// -------------------- softmax over last LP entries, one thread per (b,q,m) ------------------
__global__ void softmax_lp(float* __restrict__ a, int total, int LP) {
  int i = blockIdx.x * blockDim.x + threadIdx.x;
  if (i >= total) return;
  float* p = a + (size_t)i * LP;
  float mx = -1e30f;
  for (int j = 0; j < LP; ++j) mx = fmaxf(mx, p[j]);
  float s = 0.0f;
  for (int j = 0; j < LP; ++j) {
    float e = expf(p[j] - mx);
    p[j] = e;
    s += e;
  }
  float inv = 1.0f / s;
  for (int j = 0; j < LP; ++j) p[j] *= inv;
}

// -------------------- Injector sampling v2: 16 threads per (b,q,m), f16x8 gathers -----------
__global__ __launch_bounds__(256) void sample_inj2(const half_t* __restrict__ v,
                                                   const float* __restrict__ offs,
                                                   const float* __restrict__ aw,
                                                   half_t* __restrict__ out) {
  int tid = threadIdx.x;
  int gp = blockIdx.x * 16 + (tid >> 4);
  int lane16 = tid & 15;
  int m = gp % MH;
  int bq = gp / MH;  // b*1024+q
  int q = bq & 1023;
  int b = bq >> 10;
  float refx = ((q & 31) + 0.5f) * (1.0f / 32.0f);
  float refy = ((q >> 5) + 0.5f) * (1.0f / 32.0f);
  const float* op = offs + (size_t)gp * 24;
  const float* ap = aw + (size_t)gp * 12;
  const half_t* vb = v + (size_t)b * 5376 * CD + m * DH + lane16 * 8;
  const int Hs[3] = {64, 32, 16};
  const int Ss[3] = {0, 4096, 5120};
  float accf[8];
#pragma unroll
  for (int i = 0; i < 8; ++i) accf[i] = 0.f;
#pragma unroll
  for (int lvl = 0; lvl < 3; ++lvl) {
    int H = Hs[lvl];
    float fH = (float)H;
    const half_t* vl = vb + (size_t)Ss[lvl] * CD;
#pragma unroll
    for (int p = 0; p < 4; ++p) {
      float xx = refx * fH + op[(lvl * 4 + p) * 2 + 0] - 0.5f;
      float yy = refy * fH + op[(lvl * 4 + p) * 2 + 1] - 0.5f;
      float x0f = floorf(xx), y0f = floorf(yy);
      float wx = xx - x0f, wy = yy - y0f;
      int x0 = (int)x0f, y0 = (int)y0f;
      float a = ap[lvl * 4 + p];
      f16x8 acch = (f16x8)(half_t)0.0f;
#pragma unroll
      for (int cy = 0; cy < 2; ++cy)
#pragma unroll
        for (int cx = 0; cx < 2; ++cx) {
          int xi = x0 + cx, yi = y0 + cy;
          bool valid = (xi >= 0) & (xi < H) & (yi >= 0) & (yi < H);
          float wgt = (cx ? wx : 1.f - wx) * (cy ? wy : 1.f - wy) * a;
          int xs = min(max(xi, 0), H - 1), ys = min(max(yi, 0), H - 1);
          half_t wch = (half_t)(valid ? wgt : 0.f);
          f16x8 vv = *(const f16x8*)(vl + (size_t)(ys * H + xs) * CD);
          acch += vv * wch;
        }
#pragma unroll
      for (int i = 0; i < 8; ++i) accf[i] += (float)acch[i];
    }
  }
  f16x8 r;
#pragma unroll
  for (int i = 0; i < 8; ++i) r[i] = (half_t)accf[i];
  *(f16x8*)(out + (size_t)bq * CD + m * DH + lane16 * 8) = r;
}

// -------------------- Extractor sampling v2: 16 threads per (b,q,m) -------------------------
__global__ __launch_bounds__(256) void sample_ext2(const half_t* __restrict__ v,
                                                   const float* __restrict__ offs,
                                                   const float* __restrict__ aw,
                                                   half_t* __restrict__ out) {
  int tid = threadIdx.x;
  int gp = blockIdx.x * 16 + (tid >> 4);
  int lane16 = tid & 15;
  int m = gp % MH;
  int bq = gp / MH;  // b*5376+q
  int q = bq % 5376;
  int b = bq / 5376;
  float refx, refy;
  if (q < 4096) {
    refx = ((q & 63) + 0.5f) * (1.0f / 64.0f);
    refy = ((q >> 6) + 0.5f) * (1.0f / 64.0f);
  } else if (q < 5120) {
    int li = q - 4096;
    refx = ((li & 31) + 0.5f) * (1.0f / 32.0f);
    refy = ((li >> 5) + 0.5f) * (1.0f / 32.0f);
  } else {
    int li = q - 5120;
    refx = ((li & 15) + 0.5f) * (1.0f / 16.0f);
    refy = ((li >> 4) + 0.5f) * (1.0f / 16.0f);
  }
  const float* op = offs + (size_t)gp * 8;
  const float* ap = aw + (size_t)gp * 4;
  const half_t* vb = v + (size_t)b * 1024 * CD + m * DH + lane16 * 8;
  float accf[8];
#pragma unroll
  for (int i = 0; i < 8; ++i) accf[i] = 0.f;
#pragma unroll
  for (int p = 0; p < 4; ++p) {
    float xx = refx * 32.0f + op[p * 2 + 0] - 0.5f;
    float yy = refy * 32.0f + op[p * 2 + 1] - 0.5f;
    float x0f = floorf(xx), y0f = floorf(yy);
    float wx = xx - x0f, wy = yy - y0f;
    int x0 = (int)x0f, y0 = (int)y0f;
    float a = ap[p];
    f16x8 acch = (f16x8)(half_t)0.0f;
#pragma unroll
    for (int cy = 0; cy < 2; ++cy)
#pragma unroll
      for (int cx = 0; cx < 2; ++cx) {
        int xi = x0 + cx, yi = y0 + cy;
        bool valid = (xi >= 0) & (xi < 32) & (yi >= 0) & (yi < 32);
        float wgt = (cx ? wx : 1.f - wx) * (cy ? wy : 1.f - wy) * a;
        int xs = min(max(xi, 0), 31), ys = min(max(yi, 0), 31);
        half_t wch = (half_t)(valid ? wgt : 0.f);
        f16x8 vv = *(const f16x8*)(vb + (size_t)(ys * 32 + xs) * CD);
        acch += vv * wch;
      }
#pragma unroll
    for (int i = 0; i < 8; ++i) accf[i] += (float)acch[i];
  }
  f16x8 r;
#pragma unroll
  for (int i = 0; i < 8; ++i) r[i] = (half_t)accf[i];
  *(f16x8*)(out + (size_t)bq * CD + m * DH + lane16 * 8) = r;
}

// -------------------- depthwise 3x3 + bias + exact GELU, 8 channels/thread ------------------
// h: (B,5376,192) fp16; grid covers Sc*24 groups of 8 channels
__global__ __launch_bounds__(256) void dwconv_gelu(const half_t* __restrict__ h,
                                                   const float* __restrict__ w,
                                                   const float* __restrict__ bias,
                                                   half_t* __restrict__ out) {
  int g = blockIdx.x * 256 + threadIdx.x;
  int cg = g % 24;
  int tl = g / 24;          // b*5376 + tok
  int tok = tl % 5376;
  int b = tl / 5376;
  int H, s, li;
  if (tok < 4096) { H = 64; s = 0; li = tok; }
  else if (tok < 5120) { H = 32; s = 4096; li = tok - 4096; }
  else { H = 16; s = 5120; li = tok - 5120; }
  int y = li / H, x = li % H;
  int c0 = cg * 8;
  const half_t* hb = h + ((size_t)b * 5376 + s) * 192 + c0;
  float acc[8];
#pragma unroll
  for (int i = 0; i < 8; ++i) acc[i] = bias[c0 + i];
#pragma unroll
  for (int dy = -1; dy <= 1; ++dy) {
    int yy = y + dy;
    if (yy < 0 || yy >= H) continue;
#pragma unroll
    for (int dx = -1; dx <= 1; ++dx) {
      int xx = x + dx;
      if (xx < 0 || xx >= H) continue;
      int k = (dy + 1) * 3 + (dx + 1);
      f16x8 vv = *(const f16x8*)(hb + (size_t)(yy * H + xx) * 192);
#pragma unroll
      for (int i = 0; i < 8; ++i) acc[i] += w[(c0 + i) * 9 + k] * (float)vv[i];
    }
  }
  f16x8 r;
#pragma unroll
  for (int i = 0; i < 8; ++i)
    r[i] = (half_t)(0.5f * acc[i] * (1.0f + erff(acc[i] * 0.70710678118654752f)));
  *(f16x8*)(out + (size_t)tl * 192 + c0) = r;
}

// -------------------- host launcher --------------------
extern "C" void kernel_launch(void* const* d_in, const int* in_sizes, int n_in,
                              void* d_out, int out_size, void* d_ws, size_t ws_size,
                              hipStream_t stream) {
  (void)in_sizes; (void)n_in; (void)out_size; (void)ws_size;
  const float* x        = (const float*)d_in[0];
  const float* c        = (const float*)d_in[1];
  const float* inj_n1g  = (const float*)d_in[2];
  const float* inj_n1b  = (const float*)d_in[3];
  const float* inj_n2g  = (const float*)d_in[4];
  const float* inj_n2b  = (const float*)d_in[5];
  const float* inj_off_w = (const float*)d_in[6];
  const float* inj_off_b = (const float*)d_in[7];
  const float* inj_aw_w = (const float*)d_in[8];
  const float* inj_aw_b = (const float*)d_in[9];
  const float* inj_val_w = (const float*)d_in[10];
  const float* inj_val_b = (const float*)d_in[11];
  const float* inj_out_w = (const float*)d_in[12];
  const float* inj_out_b = (const float*)d_in[13];
  const float* ext_n1g  = (const float*)d_in[14];
  const float* ext_n1b  = (const float*)d_in[15];
  const float* ext_n2g  = (const float*)d_in[16];
  const float* ext_n2b  = (const float*)d_in[17];
  const float* ext_off_w = (const float*)d_in[18];
  const float* ext_off_b = (const float*)d_in[19];
  const float* ext_aw_w = (const float*)d_in[20];
  const float* ext_aw_b = (const float*)d_in[21];
  const float* ext_val_w = (const float*)d_in[22];
  const float* ext_val_b = (const float*)d_in[23];
  const float* ext_out_w = (const float*)d_in[24];
  const float* ext_out_b = (const float*)d_in[25];
  const float* inj_gamma = (const float*)d_in[26];
  const float* ext_ng   = (const float*)d_in[27];
  const float* ext_nb   = (const float*)d_in[28];
  const float* ext_fc1_w = (const float*)d_in[29];
  const float* ext_fc1_b = (const float*)d_in[30];
  const float* ext_dw_w = (const float*)d_in[31];
  const float* ext_dw_b = (const float*)d_in[32];
  const float* ext_fc2_w = (const float*)d_in[33];
  const float* ext_fc2_b = (const float*)d_in[34];

  const int Sx = 4096;   // B*1024
  const int Sc = 21504;  // B*5376
  float* xout = (float*)d_out;
  float* cout = (float*)d_out + (size_t)Sx * CD;

  // ---- workspace layout (~141 MB) ----
  half_t* bigA   = (half_t*)d_ws;           // 16,515,072 h  LN_inj(c) / LN(cout)
  half_t* bigA2  = bigA + 16515072;         // 16,515,072 h  LN_ext(c)
  half_t* bigV   = bigA2 + 16515072;        // 16,515,072 h  v_inj / attn_ext
  half_t* smallA = bigV + 16515072;         //  3,145,728 h  LN(x)/LN(xout)
  half_t* smallB = smallA + 3145728;        //  3,145,728 h  attn_inj / v_ext
  half_t* h16    = smallB + 3145728;        //  4,128,768 h  fc1 out
  half_t* h2     = h16 + 4128768;           //  4,128,768 h  dwconv out
  half_t* w_inj_val = h2 + 4128768;         // 589,824
  half_t* w_inj_out = w_inj_val + 589824;   // 589,824
  half_t* w_ext_val = w_inj_out + 589824;   // 589,824
  half_t* w_ext_out = w_ext_val + 589824;   // 589,824
  half_t* w_fc2     = w_ext_out + 589824;   // 147,456 (768 x 192)
  half_t* w_inj_off = w_fc2 + 147456;       // 196,608 (256 x 768)
  half_t* w_inj_aw  = w_inj_off + 196608;   //  98,304 (128 x 768)
  half_t* w_ext_off = w_inj_aw + 98304;     //  98,304
  half_t* w_ext_aw  = w_ext_off + 98304;    //  98,304
  half_t* w_fc1     = w_ext_aw + 98304;     // 196,608 (256 x 768)
  float* offsb = (float*)(((uintptr_t)(w_fc1 + 196608) + 255) & ~(uintptr_t)255);
  float* awb = offsb + 1032192;

  // ---- fused weight conversion (10 segments, one launch) ----
  ConvArgs ca;
  const float* srcs[10] = {inj_val_w, inj_off_w, inj_aw_w, inj_out_w, ext_val_w,
                           ext_off_w, ext_aw_w, ext_out_w, ext_fc1_w, ext_fc2_w};
  half_t* dsts[10] = {w_inj_val, w_inj_off, w_inj_aw, w_inj_out, w_ext_val,
                      w_ext_off, w_ext_aw, w_ext_out, w_fc1, w_fc2};
  int Ks[10]    = {768, 768, 768, 768, 768, 768, 768, 768, 768, 192};
  int Ns[10]    = {768, 144, 72, 768, 768, 48, 24, 768, 192, 768};
  int Npads[10] = {768, 256, 128, 768, 768, 128, 128, 768, 256, 768};
  int base = 0;
  for (int i = 0; i < 10; ++i) {
    ca.W[i] = srcs[i]; ca.Wt[i] = dsts[i]; ca.K[i] = Ks[i]; ca.N[i] = Ns[i];
    ca.base[i] = base; base += Npads[i] * Ks[i];
  }
  ca.base[10] = base;
  convert_all<<<(base + 255) / 256, 256, 0, stream>>>(ca);

  // ---------------- Phase 1: Injector ----------------
  ln_f16<<<Sx, 256, 0, stream>>>(x, inj_n1g, inj_n1b, smallA);
  ln_dual<<<Sc, 256, 0, stream>>>(c, inj_n2g, inj_n2b, bigA, ext_n1g, ext_n1b, bigA2);
  gemm_mfma<0, 1><<<dim3(6, 168), 256, 0, stream>>>(bigA, w_inj_val, inj_val_b, nullptr, nullptr, bigV, Sc, 768, 768);
  gemm_mfma<0, 0><<<dim3(2, 32), 256, 0, stream>>>(smallA, w_inj_off, inj_off_b, nullptr, nullptr, offsb, Sx, 144, 768);
  gemm_mfma<0, 0><<<dim3(1, 32), 256, 0, stream>>>(smallA, w_inj_aw, inj_aw_b, nullptr, nullptr, awb, Sx, 72, 768);
  softmax_lp<<<(Sx * MH + 255) / 256, 256, 0, stream>>>(awb, Sx * MH, 12);
  sample_inj2<<<(Sx * MH) / 16, 256, 0, stream>>>(bigV, offsb, awb, smallB);
  gemm_mfma<1, 0><<<dim3(6, 32), 256, 0, stream>>>(smallB, w_inj_out, inj_out_b, x, inj_gamma, xout, Sx, 768, 768);

  // ---------------- Phase 2: Extractor ----------------
  ln_f16<<<Sx, 256, 0, stream>>>(xout, ext_n2g, ext_n2b, smallA);
  gemm_mfma<0, 1><<<dim3(6, 32), 256, 0, stream>>>(smallA, w_ext_val, ext_val_b, nullptr, nullptr, smallB, Sx, 768, 768);
  gemm_mfma<0, 0><<<dim3(1, 168), 256, 0, stream>>>(bigA2, w_ext_off, ext_off_b, nullptr, nullptr, offsb, Sc, 48, 768);
  gemm_mfma<0, 0><<<dim3(1, 168), 256, 0, stream>>>(bigA2, w_ext_aw, ext_aw_b, nullptr, nullptr, awb, Sc, 24, 768);
  softmax_lp<<<(Sc * MH + 255) / 256, 256, 0, stream>>>(awb, Sc * MH, 4);
  sample_ext2<<<(Sc * MH) / 16, 256, 0, stream>>>(smallB, offsb, awb, bigV);
  gemm_mfma<2, 0><<<dim3(6, 168), 256, 0, stream>>>(bigV, w_ext_out, ext_out_b, c, nullptr, cout, Sc, 768, 768);

  // ---------------- Phase 3: ConvFFN ----------------
  ln_f16<<<Sc, 256, 0, stream>>>(cout, ext_ng, ext_nb, bigA);
  gemm_mfma<0, 1><<<dim3(2, 168), 256, 0, stream>>>(bigA, w_fc1, ext_fc1_b, nullptr, nullptr, h16, Sc, 192, 768);
  dwconv_gelu<<<(Sc * 24) / 256, 256, 0, stream>>>(h16, ext_dw_w, ext_dw_b, h2);
  gemm_mfma<2, 0><<<dim3(6, 168), 256, 0, stream>>>(h2, w_fc2, ext_fc2_b, cout, nullptr, cout, Sc, 768, 192);
}